// Round 3
// baseline (1493.320 us; speedup 1.0000x reference)
//
#include <hip/hip_runtime.h>
#include <stdint.h>

// ---------------------------------------------------------------------------
// SpatialGNN forward, round 3.
// R2 gave NaN -> diagnosis: float inputs are (likely) fp32, not bf16; reading
// fp32 as bf16 pairs decodes mantissa noise into NaN/Inf bf16 values.
// This round removes BOTH ambiguities at runtime:
//  - host: argument order from in_sizes[1] (200000=dict order, 100000=ref
//    signature order with edge_index second)
//  - device: dtype flag from edge_attr statistics (uniform[0,1): bf16 words
//    have low16 in [0x3A00,0x4000); fp32 low16 is uniform noise), then one
//    conversion pass into canonical fp32 arrays; output written per flag.
// Compute scheme (unchanged from R2):
//   T[n,o,k] = sum_i x[n,i]*W2[i*64+o,k]  (k-chunked, bf16 MFMA)
//   m[e,o]   = sum_k s[e,k]*T[src,o,k];  agg[dst] += m + xb2[src]; /deg
//   xc = silu(x@rootW.T + b + agg); GRU; Set2Set; head.
// ---------------------------------------------------------------------------

#define NN 10000
#define EE 50000
#define BBG 512

typedef __attribute__((ext_vector_type(8))) short short8;
typedef __attribute__((ext_vector_type(4))) float f32x4;
typedef __attribute__((ext_vector_type(2))) float f32x2;

__device__ __forceinline__ float b2f(unsigned short u) {
  return __uint_as_float(((unsigned)u) << 16);
}
__device__ __forceinline__ float b2f_lo(unsigned u) { return __uint_as_float(u << 16); }
__device__ __forceinline__ float b2f_hi(unsigned u) { return __uint_as_float(u & 0xFFFF0000u); }
__device__ __forceinline__ unsigned short f2b(float f) {
  unsigned u = __float_as_uint(f);
  u += 0x7FFFu + ((u >> 16) & 1u);  // RNE
  return (unsigned short)(u >> 16);
}
__device__ __forceinline__ float sigm(float x) { return 1.0f / (1.0f + __expf(-x)); }
__device__ __forceinline__ float siluf(float x) { return x / (1.0f + __expf(-x)); }

__device__ __forceinline__ unsigned encf(float f) {  // monotone float->uint
  unsigned u = __float_as_uint(f);
  return (u & 0x80000000u) ? ~u : (u | 0x80000000u);
}
__device__ __forceinline__ float decf(unsigned u) {
  unsigned b = (u & 0x80000000u) ? (u & 0x7FFFFFFFu) : ~u;
  return __uint_as_float(b);
}

// ---------------- dtype detection on edge_attr (uniform[0,1)) --------------
__global__ __launch_bounds__(256) void k_detect(const unsigned* __restrict__ w,
                                                int* __restrict__ flag) {
  __shared__ int cnt;
  if (threadIdx.x == 0) cnt = 0;
  __syncthreads();
  int c = 0;
  for (int i = threadIdx.x; i < 4096; i += 256) {
    unsigned lo = w[i] & 0xFFFFu;
    if (lo - 0x3A00u < 0x600u) c++;  // [0x3A00, 0x4000): bf16 of [~5e-4, 1)
  }
  atomicAdd(&cnt, c);
  __syncthreads();
  if (threadIdx.x == 0) *flag = (cnt > 2048) ? 1 : 0;  // 1 = inputs are bf16
}

// ---------------- convert all float inputs to canonical fp32 ---------------
#define NCVT 23
struct Cvt {
  const void* src[NCVT];
  float* dst[NCVT];
  int n[NCVT];
};

__global__ __launch_bounds__(256) void k_convert(Cvt c, const int* __restrict__ flag) {
  const int f = *flag;
  const int stride = gridDim.x * blockDim.x;
  const int tid = blockIdx.x * blockDim.x + threadIdx.x;
#pragma unroll 1
  for (int a = 0; a < NCVT; a++) {
    const int n = c.n[a];
    const float* sf = (const float*)c.src[a];
    const unsigned short* sb = (const unsigned short*)c.src[a];
    float* d = c.dst[a];
    for (int i = tid; i < n; i += stride) d[i] = f ? b2f(sb[i]) : sf[i];
  }
}

// ---------------- feature lift: x = silu(x_in @ fl_W.T + fl_b) -------------
__global__ __launch_bounds__(256) void k_lift(const float* __restrict__ xin,
                                              const float* __restrict__ flW,
                                              const float* __restrict__ flb,
                                              float* __restrict__ x,
                                              unsigned short* __restrict__ xb) {
  int node = blockIdx.x * 4 + (threadIdx.x >> 6);
  int h = threadIdx.x & 63;
  float acc = flb[h];
#pragma unroll
  for (int c = 0; c < 11; c++)
    acc += xin[node * 11 + c] * flW[h * 11 + c];
  float v = siluf(acc);
  x[node * 64 + h] = v;
  xb[node * 64 + h] = f2b(v);
}

// ---------- s[e,k] = silu(ef @ nn_W1.T + nn_b1) bf16, deg atomic -----------
__global__ __launch_bounds__(128) void k_sdeg(const float* __restrict__ ea,
                                              const float* __restrict__ pos,
                                              const int* __restrict__ ei,
                                              const float* __restrict__ W1,
                                              const float* __restrict__ b1,
                                              unsigned short* __restrict__ s_bf,
                                              float* __restrict__ deg) {
  int e = blockIdx.x;
  int k = threadIdx.x;
  int src = ei[e], dst = ei[EE + e];
  float dx = pos[src * 3 + 0] - pos[dst * 3 + 0];
  float dy = pos[src * 3 + 1] - pos[dst * 3 + 1];
  float dz = pos[src * 3 + 2] - pos[dst * 3 + 2];
  float dist = sqrtf(dx * dx + dy * dy + dz * dz);
  float acc = b1[k];
  acc += ea[e * 4 + 0] * W1[k * 5 + 0];
  acc += ea[e * 4 + 1] * W1[k * 5 + 1];
  acc += ea[e * 4 + 2] * W1[k * 5 + 2];
  acc += ea[e * 4 + 3] * W1[k * 5 + 3];
  acc += dist * W1[k * 5 + 4];
  s_bf[e * 128 + k] = f2b(siluf(acc));
  if (k == 0) atomicAdd(deg + dst, 1.0f);
}

__global__ __launch_bounds__(256) void k_invdeg(const float* __restrict__ deg,
                                                float* __restrict__ inv) {
  int n = blockIdx.x * 256 + threadIdx.x;
  if (n < NN) inv[n] = 1.0f / fmaxf(deg[n], 1.0f);
}

// ---- W2t[(o*128+k)*64 + i] = bf16(W2[(i*64+o)*128 + k])  (1MB, once) ------
__global__ __launch_bounds__(256) void k_w2t(const float* __restrict__ W2,
                                             unsigned short* __restrict__ W2t) {
  int j = blockIdx.x * 256 + threadIdx.x;  // 64*128*64
  int i = j & 63;
  int k = (j >> 6) & 127;
  int o = j >> 13;
  W2t[j] = f2b(W2[(size_t)(i * 64 + o) * 128 + k]);
}

// ---- xb2[n,o] = sum_i x[n,i] * b2[i*64+o] ---------------------------------
__global__ __launch_bounds__(256) void k_xb2(const float* __restrict__ x,
                                             const float* __restrict__ b2,
                                             float* __restrict__ xb2) {
  int node = blockIdx.x * 4 + (threadIdx.x >> 6);
  int o = threadIdx.x & 63;
  int xvi = __float_as_int(x[node * 64 + o]);  // lane's o doubles as i-slot
  float acc = 0.0f;
#pragma unroll 8
  for (int i = 0; i < 64; i++) {
    float xi = __int_as_float(__builtin_amdgcn_readlane(xvi, i));
    acc += xi * b2[i * 64 + o];
  }
  xb2[node * 64 + o] = acc;
}

// ---- T chunk GEMM: Tc[n][c] = sum_i xb[n,i]*W2t[(o*128+K0+c%KC)*64+i] -----
template <int KC>
__global__ __launch_bounds__(256) void k_T(const unsigned short* __restrict__ xb,
                                           const unsigned short* __restrict__ W2t,
                                           unsigned short* __restrict__ Tc, int K0) {
  __shared__ unsigned short As[128 * 72];  // [node][i]
  __shared__ unsigned short Bs[128 * 72];  // [c_local][i]
  const int t = threadIdx.x;
  const int n0 = blockIdx.x * 128;
  const int c0 = blockIdx.y * 128;
  const int lane = t & 63;
  const int w = t >> 6;
  const int lm = lane & 15;
  const int quad = lane >> 4;
  const int wm = w & 1;
  const int wn = w >> 1;

  for (int p = t; p < 128 * 8; p += 256) {
    int r = p >> 3, cc = (p & 7) * 8;
    uint4 v = make_uint4(0u, 0u, 0u, 0u);
    if (n0 + r < NN) v = *reinterpret_cast<const uint4*>(xb + (size_t)(n0 + r) * 64 + cc);
    *reinterpret_cast<uint4*>(&As[r * 72 + cc]) = v;
  }
  for (int p = t; p < 128 * 8; p += 256) {
    int r = p >> 3, cc = (p & 7) * 8;
    int c = c0 + r;
    int o = c / KC;
    int kg = K0 + (c % KC);
    uint4 v = *reinterpret_cast<const uint4*>(W2t + (size_t)(o * 128 + kg) * 64 + cc);
    *reinterpret_cast<uint4*>(&Bs[r * 72 + cc]) = v;
  }
  __syncthreads();

  f32x4 acc[4][4];
#pragma unroll
  for (int mt = 0; mt < 4; mt++)
#pragma unroll
    for (int nt = 0; nt < 4; nt++) acc[mt][nt] = (f32x4)(0.0f);

#pragma unroll
  for (int ks = 0; ks < 2; ks++) {
    const int kk = ks * 32 + quad * 8;
    short8 af[4], bfr[4];
#pragma unroll
    for (int mt = 0; mt < 4; mt++)
      af[mt] = *reinterpret_cast<const short8*>(&As[(wm * 64 + mt * 16 + lm) * 72 + kk]);
#pragma unroll
    for (int nt = 0; nt < 4; nt++)
      bfr[nt] = *reinterpret_cast<const short8*>(&Bs[(wn * 64 + nt * 16 + lm) * 72 + kk]);
#pragma unroll
    for (int mt = 0; mt < 4; mt++)
#pragma unroll
      for (int nt = 0; nt < 4; nt++)
        acc[mt][nt] = __builtin_amdgcn_mfma_f32_16x16x32_bf16(af[mt], bfr[nt], acc[mt][nt], 0, 0, 0);
  }

#pragma unroll
  for (int nt = 0; nt < 4; nt++) {
    int c = c0 + wn * 64 + nt * 16 + lm;
#pragma unroll
    for (int mt = 0; mt < 4; mt++) {
#pragma unroll
      for (int reg = 0; reg < 4; reg++) {
        int n = n0 + wm * 64 + mt * 16 + quad * 4 + reg;
        if (n < NN) Tc[(size_t)n * (64 * KC) + c] = f2b(acc[mt][nt][reg]);
      }
    }
  }
}

// ---- per-edge chunk dot: m[e,o] (+)= sum_{kk<KC} s[e,K0+kk]*Tc[src,o,kk] --
template <int KC>
__global__ __launch_bounds__(256) void k_emsg(const unsigned short* __restrict__ Tc,
                                              const unsigned short* __restrict__ s_bf,
                                              const int* __restrict__ ei,
                                              float* __restrict__ m, int K0, int first) {
  int e = blockIdx.x * 4 + (threadIdx.x >> 6);
  int o = threadIdx.x & 63;
  int src = ei[e];
  const uint4* tv = reinterpret_cast<const uint4*>(Tc + ((size_t)src * 64 + o) * KC);
  const uint4* sv = reinterpret_cast<const uint4*>(s_bf + (size_t)e * 128 + K0);
  float acc = 0.0f;
#pragma unroll
  for (int j = 0; j < KC / 8; j++) {
    uint4 a = tv[j], b = sv[j];
    unsigned aa[4] = {a.x, a.y, a.z, a.w};
    unsigned bb[4] = {b.x, b.y, b.z, b.w};
#pragma unroll
    for (int q = 0; q < 4; q++)
      acc += b2f_lo(aa[q]) * b2f_lo(bb[q]) + b2f_hi(aa[q]) * b2f_hi(bb[q]);
  }
  float* mp = m + (size_t)e * 64 + o;
  if (first) *mp = acc;
  else *mp += acc;
}

// ---- agg[dst,o] += m[e,o] + xb2[src,o] ------------------------------------
__global__ __launch_bounds__(256) void k_aggm(const float* __restrict__ m,
                                              const float* __restrict__ xb2,
                                              const int* __restrict__ ei,
                                              float* __restrict__ agg) {
  int e = blockIdx.x * 4 + (threadIdx.x >> 6);
  int o = threadIdx.x & 63;
  int src = ei[e], dst = ei[EE + e];
  atomicAdd(agg + (size_t)dst * 64 + o, m[(size_t)e * 64 + o] + xb2[(size_t)src * 64 + o]);
}

// -------- xc = silu(x @ root_W.T + root_b + agg*inv_deg) -------------------
__global__ __launch_bounds__(256) void k_xc(const float* __restrict__ x,
                                            const float* __restrict__ agg,
                                            const float* __restrict__ invd,
                                            const float* __restrict__ rootW,
                                            const float* __restrict__ rootb,
                                            float* __restrict__ xc) {
  __shared__ float At[64 * 34];
  __shared__ float Bt[64 * 68];
  const int t = threadIdx.x;
  const int n0 = blockIdx.x * 32;
  for (int p = t; p < 32 * 64; p += 256) {
    int n = p >> 6, k = p & 63;
    At[k * 34 + n] = (n0 + n < NN) ? x[(n0 + n) * 64 + k] : 0.0f;
  }
  for (int p = t; p < 64 * 64; p += 256) {
    int o = p >> 6, k = p & 63;
    Bt[k * 68 + o] = rootW[p];
  }
  __syncthreads();
  const int tn = t >> 4, to = t & 15;
  float acc[2][4] = {{0, 0, 0, 0}, {0, 0, 0, 0}};
  for (int k = 0; k < 64; k++) {
    f32x2 a = *reinterpret_cast<const f32x2*>(&At[k * 34 + tn * 2]);
    f32x4 b = *reinterpret_cast<const f32x4*>(&Bt[k * 68 + to * 4]);
#pragma unroll
    for (int j = 0; j < 4; j++) {
      acc[0][j] += a[0] * b[j];
      acc[1][j] += a[1] * b[j];
    }
  }
#pragma unroll
  for (int nn = 0; nn < 2; nn++) {
    int n = n0 + tn * 2 + nn;
    if (n < NN) {
      float idv = invd[n];
      f32x4 outv;
#pragma unroll
      for (int j = 0; j < 4; j++) {
        int o = to * 4 + j;
        float v = acc[nn][j] + rootb[o] + agg[(size_t)n * 64 + o] * idv;
        outv[j] = siluf(v);
      }
      *reinterpret_cast<f32x4*>(xc + n * 64 + to * 4) = outv;
    }
  }
}

// -------- fused GRU --------------------------------------------------------
__global__ __launch_bounds__(256) void k_gru(const float* __restrict__ xc,
                                             float* x, unsigned short* __restrict__ xb,
                                             const float* __restrict__ Wih,
                                             const float* __restrict__ Whh,
                                             const float* __restrict__ bih,
                                             const float* __restrict__ bhh) {
  __shared__ float At[64 * 34];
  __shared__ float Bt[64 * 200];
  const int t = threadIdx.x;
  const int n0 = blockIdx.x * 32;
  const int tn = t >> 4, to = t & 15;

  for (int p = t; p < 32 * 64; p += 256) {
    int n = p >> 6, k = p & 63;
    At[k * 34 + n] = (n0 + n < NN) ? xc[(n0 + n) * 64 + k] : 0.0f;
  }
  for (int p = t; p < 192 * 64; p += 256) {
    int o = p >> 6, k = p & 63;
    Bt[k * 200 + o] = Wih[p];
  }
  __syncthreads();
  float ai[2][3][4], ah[2][3][4];
#pragma unroll
  for (int j = 0; j < 3; j++)
#pragma unroll
    for (int hh = 0; hh < 4; hh++) {
      float bv = bih[j * 64 + to * 4 + hh];
      ai[0][j][hh] = bv; ai[1][j][hh] = bv;
      float bv2 = bhh[j * 64 + to * 4 + hh];
      ah[0][j][hh] = bv2; ah[1][j][hh] = bv2;
    }
  for (int k = 0; k < 64; k++) {
    f32x2 a = *reinterpret_cast<const f32x2*>(&At[k * 34 + tn * 2]);
#pragma unroll
    for (int j = 0; j < 3; j++) {
      f32x4 b = *reinterpret_cast<const f32x4*>(&Bt[k * 200 + j * 64 + to * 4]);
#pragma unroll
      for (int hh = 0; hh < 4; hh++) {
        ai[0][j][hh] += a[0] * b[hh];
        ai[1][j][hh] += a[1] * b[hh];
      }
    }
  }
  __syncthreads();
  for (int p = t; p < 32 * 64; p += 256) {
    int n = p >> 6, k = p & 63;
    At[k * 34 + n] = (n0 + n < NN) ? x[(n0 + n) * 64 + k] : 0.0f;
  }
  for (int p = t; p < 192 * 64; p += 256) {
    int o = p >> 6, k = p & 63;
    Bt[k * 200 + o] = Whh[p];
  }
  __syncthreads();
  for (int k = 0; k < 64; k++) {
    f32x2 a = *reinterpret_cast<const f32x2*>(&At[k * 34 + tn * 2]);
#pragma unroll
    for (int j = 0; j < 3; j++) {
      f32x4 b = *reinterpret_cast<const f32x4*>(&Bt[k * 200 + j * 64 + to * 4]);
#pragma unroll
      for (int hh = 0; hh < 4; hh++) {
        ah[0][j][hh] += a[0] * b[hh];
        ah[1][j][hh] += a[1] * b[hh];
      }
    }
  }
#pragma unroll
  for (int nn = 0; nn < 2; nn++) {
    int n = n0 + tn * 2 + nn;
    if (n < NN) {
      f32x4 xn;
#pragma unroll
      for (int hh = 0; hh < 4; hh++) {
        float r = sigm(ai[nn][0][hh] + ah[nn][0][hh]);
        float z = sigm(ai[nn][1][hh] + ah[nn][1][hh]);
        float ng = tanhf(ai[nn][2][hh] + r * ah[nn][2][hh]);
        float hold = At[(to * 4 + hh) * 34 + tn * 2 + nn];
        xn[hh] = (1.0f - z) * ng + z * hold;
      }
      *reinterpret_cast<f32x4*>(x + n * 64 + to * 4) = xn;
      unsigned p0 = (unsigned)f2b(xn[0]) | ((unsigned)f2b(xn[1]) << 16);
      unsigned p1 = (unsigned)f2b(xn[2]) | ((unsigned)f2b(xn[3]) << 16);
      *reinterpret_cast<uint2*>(xb + (size_t)n * 64 + to * 4) = make_uint2(p0, p1);
    }
  }
}

// ------------------------------- Set2Set -----------------------------------
__global__ __launch_bounds__(64) void k_lstm(const float* __restrict__ qs,
                                             const float* __restrict__ Wih,
                                             const float* __restrict__ Whh,
                                             const float* __restrict__ bih,
                                             const float* __restrict__ bhh,
                                             float* hl, float* cl) {
  int b = blockIdx.x, lane = threadIdx.x;
  float g[4];
#pragma unroll
  for (int j = 0; j < 4; j++) {
    int row = j * 64 + lane;
    float acc = bih[row] + bhh[row];
    for (int k = 0; k < 128; k++) acc += qs[b * 128 + k] * Wih[row * 128 + k];
    for (int k = 0; k < 64; k++) acc += hl[b * 64 + k] * Whh[row * 64 + k];
    g[j] = acc;
  }
  float ig = sigm(g[0]), fg = sigm(g[1]), gg = tanhf(g[2]), og = sigm(g[3]);
  float c = fg * cl[b * 64 + lane] + ig * gg;
  cl[b * 64 + lane] = c;
  hl[b * 64 + lane] = og * tanhf(c);
}

__global__ __launch_bounds__(256) void k_edot(const float* __restrict__ x,
                                              const float* __restrict__ hl,
                                              const int* __restrict__ batch,
                                              float* __restrict__ e_buf,
                                              unsigned* __restrict__ mmax) {
  int node = blockIdx.x * 4 + (threadIdx.x >> 6);
  int lane = threadIdx.x & 63;
  int b = batch[node];
  float v = x[node * 64 + lane] * hl[b * 64 + lane];
#pragma unroll
  for (int mm = 32; mm; mm >>= 1) v += __shfl_xor(v, mm, 64);
  if (lane == 0) {
    e_buf[node] = v;
    atomicMax(mmax + b, encf(v));
  }
}

__global__ __launch_bounds__(256) void k_asum(const float* __restrict__ e_buf,
                                              const int* __restrict__ batch,
                                              const unsigned* __restrict__ mmax,
                                              float* __restrict__ a_buf,
                                              float* __restrict__ asum) {
  int n = blockIdx.x * 256 + threadIdx.x;
  if (n < NN) {
    int b = batch[n];
    unsigned u = mmax[b];
    float ev = e_buf[n];
    float mx = (u == 0u) ? ev : decf(u);  // safety: untouched slot -> a=1
    float a = __expf(ev - mx);
    a_buf[n] = a;
    atomicAdd(asum + b, a);
  }
}

__global__ __launch_bounds__(256) void k_rread(const float* __restrict__ x,
                                               const int* __restrict__ batch,
                                               const float* __restrict__ a_buf,
                                               const float* __restrict__ asum,
                                               float* __restrict__ rr) {
  int node = blockIdx.x * 4 + (threadIdx.x >> 6);
  int lane = threadIdx.x & 63;
  int b = batch[node];
  float wgt = a_buf[node] / asum[b];
  atomicAdd(rr + (size_t)b * 64 + lane, wgt * x[node * 64 + lane]);
}

__global__ __launch_bounds__(64) void k_qstar(const float* __restrict__ hl,
                                              const float* __restrict__ rr,
                                              float* __restrict__ qs) {
  int b = blockIdx.x, lane = threadIdx.x;
  qs[b * 128 + lane] = hl[b * 64 + lane];
  qs[b * 128 + 64 + lane] = rr[b * 64 + lane];
}

__global__ __launch_bounds__(64) void k_out(const float* __restrict__ qs,
                                            const float* __restrict__ W1,
                                            const float* __restrict__ b1,
                                            const float* __restrict__ W2,
                                            const float* __restrict__ b2o,
                                            void* __restrict__ out,
                                            const int* __restrict__ flag) {
  int b = blockIdx.x, lane = threadIdx.x;
  float acc = b1[lane];
  for (int k = 0; k < 128; k++) acc += qs[b * 128 + k] * W1[lane * 128 + k];
  float u = siluf(acc) * W2[lane];
#pragma unroll
  for (int mm = 32; mm; mm >>= 1) u += __shfl_xor(u, mm, 64);
  if (lane == 0) {
    float v = u + b2o[0];
    if (*flag) ((unsigned short*)out)[b] = f2b(v);
    else ((float*)out)[b] = v;
  }
}

// ---------------------------------------------------------------------------
template <int KC>
static void run_chunks(const unsigned short* xb, const unsigned short* W2t,
                       unsigned short* Tc, const unsigned short* s_bf,
                       const int* ei, float* m, hipStream_t stream) {
  const int nch = 128 / KC;
  for (int c = 0; c < nch; c++) {
    k_T<KC><<<dim3((NN + 127) / 128, (64 * KC) / 128), 256, 0, stream>>>(xb, W2t, Tc, c * KC);
    k_emsg<KC><<<EE / 4, 256, 0, stream>>>(Tc, s_bf, ei, m, c * KC, c == 0 ? 1 : 0);
  }
}

extern "C" void kernel_launch(void* const* d_in, const int* in_sizes, int n_in,
                              void* d_out, int out_size, void* d_ws, size_t ws_size,
                              hipStream_t stream) {
  (void)n_in; (void)out_size;
  // ---- argument-order resolution (dict vs reference-signature order) ----
  // dict order:      x, edge_attr(200000), pos, edge_index, batch, weights...
  // signature order: x, edge_index(100000), edge_attr, pos, batch, weights...
  const bool sig_order = (in_sizes[1] == 2 * EE);
  const void* p_x   = d_in[0];
  const void* p_ea  = sig_order ? d_in[2] : d_in[1];
  const void* p_pos = sig_order ? d_in[3] : d_in[2];
  const int* edge_index = (const int*)(sig_order ? d_in[1] : d_in[3]);
  const int* batch      = (const int*)d_in[4];
  const void* p_w[20];
  for (int i = 0; i < 20; i++) p_w[i] = d_in[5 + i];

  // ---- workspace layout ----
  char* base = (char*)d_ws;
  size_t off = 0;
  auto alloc = [&](size_t bytes) -> char* {
    char* p = base + off;
    off = (off + bytes + 255) & ~(size_t)255;
    return p;
  };
  int* flag = (int*)alloc(4);
  // canonical fp32 copies of all float inputs
  static const int cvt_n[NCVT] = {
      NN * 11, EE * 4, NN * 3,                    // x, edge_attr, pos
      64 * 11, 64, 128 * 5, 128, 4096 * 128, 4096, // fl_W, fl_b, nn_W1, nn_b1, nn_W2, nn_b2
      64 * 64, 64,                                 // root_W, root_b
      192 * 64, 192 * 64, 192, 192,                // gru Wih, Whh, bih, bhh
      256 * 128, 256 * 64, 256, 256,               // lstm Wih, Whh, bih, bhh
      64 * 128, 64, 64, 1};                        // out_W1, out_b1, out_W2, out_b2
  float* canon[NCVT];
  for (int i = 0; i < NCVT; i++) canon[i] = (float*)alloc((size_t)cvt_n[i] * 4);
  const float* c_x    = canon[0];
  const float* c_ea   = canon[1];
  const float* c_pos  = canon[2];
  const float* c_flW  = canon[3];
  const float* c_flb  = canon[4];
  const float* c_W1   = canon[5];
  const float* c_b1   = canon[6];
  const float* c_W2   = canon[7];
  const float* c_b2   = canon[8];
  const float* c_rW   = canon[9];
  const float* c_rb   = canon[10];
  const float* c_gWih = canon[11];
  const float* c_gWhh = canon[12];
  const float* c_gbih = canon[13];
  const float* c_gbhh = canon[14];
  const float* c_lWih = canon[15];
  const float* c_lWhh = canon[16];
  const float* c_lbih = canon[17];
  const float* c_lbhh = canon[18];
  const float* c_oW1  = canon[19];
  const float* c_ob1  = canon[20];
  const float* c_oW2  = canon[21];
  const float* c_ob2  = canon[22];

  unsigned short* s_bf = (unsigned short*)alloc((size_t)EE * 128 * 2);  // 12.8MB
  float* m    = (float*)alloc((size_t)EE * 64 * 4);                     // 12.8MB
  float* x    = (float*)alloc((size_t)NN * 64 * 4);
  unsigned short* xb = (unsigned short*)alloc((size_t)NN * 64 * 2);
  float* xc   = (float*)alloc((size_t)NN * 64 * 4);
  float* agg  = (float*)alloc((size_t)NN * 64 * 4);
  float* xb2  = (float*)alloc((size_t)NN * 64 * 4);
  unsigned short* W2t = (unsigned short*)alloc((size_t)4096 * 128 * 2); // 1MB
  float* deg  = (float*)alloc((size_t)NN * 4);
  float* invd = (float*)alloc((size_t)NN * 4);
  float* hl   = (float*)alloc((size_t)BBG * 64 * 4);   // hl,cl,qs contiguous
  float* cl   = (float*)alloc((size_t)BBG * 64 * 4);
  float* qs   = (float*)alloc((size_t)BBG * 128 * 4);
  unsigned* mmax = (unsigned*)alloc((size_t)BBG * 4);  // mmax,asum,rr contiguous
  float* asum = (float*)alloc((size_t)BBG * 4);
  float* rr   = (float*)alloc((size_t)BBG * 64 * 4);
  float* e_buf = (float*)alloc((size_t)NN * 4);
  float* a_buf = (float*)alloc((size_t)NN * 4);
  size_t base_need = off;

  int KC = 0;
  const int kcs[5] = {128, 64, 32, 16, 8};
  for (int i = 0; i < 5; i++) {
    size_t need = base_need + (size_t)NN * 64 * kcs[i] * 2 + 256;
    if (need <= ws_size) { KC = kcs[i]; break; }
  }
  if (KC == 0) return;  // ws too small: diagnostic (stub-identical error)
  unsigned short* Tc = (unsigned short*)alloc((size_t)NN * 64 * KC * 2);

  // ---- dtype detect + convert ----
  k_detect<<<1, 256, 0, stream>>>((const unsigned*)p_ea, flag);
  Cvt cvt;
  cvt.src[0] = p_x; cvt.src[1] = p_ea; cvt.src[2] = p_pos;
  for (int i = 0; i < 20; i++) cvt.src[3 + i] = p_w[i];
  for (int i = 0; i < NCVT; i++) { cvt.dst[i] = canon[i]; cvt.n[i] = cvt_n[i]; }
  k_convert<<<512, 256, 0, stream>>>(cvt, flag);

  // ---- prologue ----
  hipMemsetAsync(deg, 0, (size_t)NN * 4, stream);
  k_lift<<<NN / 4, 256, 0, stream>>>(c_x, c_flW, c_flb, x, xb);
  k_sdeg<<<EE, 128, 0, stream>>>(c_ea, c_pos, edge_index, c_W1, c_b1, s_bf, deg);
  k_invdeg<<<(NN + 255) / 256, 256, 0, stream>>>(deg, invd);
  k_w2t<<<(4096 * 128) / 256, 256, 0, stream>>>(c_W2, W2t);

  // ---- 4 message-passing layers ----
  for (int layer = 0; layer < 4; layer++) {
    hipMemsetAsync(agg, 0, (size_t)NN * 64 * 4, stream);
    switch (KC) {
      case 128: run_chunks<128>(xb, W2t, Tc, s_bf, edge_index, m, stream); break;
      case 64:  run_chunks<64>(xb, W2t, Tc, s_bf, edge_index, m, stream); break;
      case 32:  run_chunks<32>(xb, W2t, Tc, s_bf, edge_index, m, stream); break;
      case 16:  run_chunks<16>(xb, W2t, Tc, s_bf, edge_index, m, stream); break;
      default:  run_chunks<8>(xb, W2t, Tc, s_bf, edge_index, m, stream); break;
    }
    k_xb2<<<NN / 4, 256, 0, stream>>>(x, c_b2, xb2);
    k_aggm<<<EE / 4, 256, 0, stream>>>(m, xb2, edge_index, agg);
    k_xc<<<(NN + 31) / 32, 256, 0, stream>>>(x, agg, invd, c_rW, c_rb, xc);
    k_gru<<<(NN + 31) / 32, 256, 0, stream>>>(xc, x, xb, c_gWih, c_gWhh, c_gbih, c_gbhh);
  }

  // ---- Set2Set ----
  hipMemsetAsync(hl, 0, (size_t)(BBG * 64 + BBG * 64 + BBG * 128) * 4, stream);
  for (int step = 0; step < 3; step++) {
    hipMemsetAsync(mmax, 0, (size_t)(BBG + BBG + BBG * 64) * 4, stream);
    k_lstm<<<BBG, 64, 0, stream>>>(qs, c_lWih, c_lWhh, c_lbih, c_lbhh, hl, cl);
    k_edot<<<NN / 4, 256, 0, stream>>>(x, hl, batch, e_buf, mmax);
    k_asum<<<(NN + 255) / 256, 256, 0, stream>>>(e_buf, batch, mmax, a_buf, asum);
    k_rread<<<NN / 4, 256, 0, stream>>>(x, batch, a_buf, asum, rr);
    k_qstar<<<BBG, 64, 0, stream>>>(hl, rr, qs);
  }

  // ---- output head ----
  k_out<<<BBG, 64, 0, stream>>>(qs, c_oW1, c_ob1, c_oW2, c_ob2, d_out, flag);
}

// Round 4
// 1022.911 us; speedup vs baseline: 1.4599x; 1.4599x over previous
//
#include <hip/hip_runtime.h>
#include <stdint.h>

// ---------------------------------------------------------------------------
// SpatialGNN forward, round 4.
// R3 passed (1493us). k_emsg x4 = 668us, re-reading Tc ~5x (avg degree).
// R4: src-grouped edge pass via device-built CSR. One 64-thread block per
// node keeps its T row (16KB) in VGPRs, loops its out-edges, adds message
// (+ xb2 bias) directly into agg[dst] atomically. Removes m buffer + k_aggm.
// Tc now read exactly once per layer (164MB instead of 800MB logical).
// ---------------------------------------------------------------------------

#define NN 10000
#define EE 50000
#define BBG 512

typedef __attribute__((ext_vector_type(8))) short short8;
typedef __attribute__((ext_vector_type(4))) float f32x4;
typedef __attribute__((ext_vector_type(2))) float f32x2;

__device__ __forceinline__ float b2f(unsigned short u) {
  return __uint_as_float(((unsigned)u) << 16);
}
__device__ __forceinline__ float b2f_lo(unsigned u) { return __uint_as_float(u << 16); }
__device__ __forceinline__ float b2f_hi(unsigned u) { return __uint_as_float(u & 0xFFFF0000u); }
__device__ __forceinline__ unsigned short f2b(float f) {
  unsigned u = __float_as_uint(f);
  u += 0x7FFFu + ((u >> 16) & 1u);  // RNE
  return (unsigned short)(u >> 16);
}
__device__ __forceinline__ float sigm(float x) { return 1.0f / (1.0f + __expf(-x)); }
__device__ __forceinline__ float siluf(float x) { return x / (1.0f + __expf(-x)); }

__device__ __forceinline__ unsigned encf(float f) {  // monotone float->uint
  unsigned u = __float_as_uint(f);
  return (u & 0x80000000u) ? ~u : (u | 0x80000000u);
}
__device__ __forceinline__ float decf(unsigned u) {
  unsigned b = (u & 0x80000000u) ? (u & 0x7FFFFFFFu) : ~u;
  return __uint_as_float(b);
}

// ---------------- dtype detection on edge_attr (uniform[0,1)) --------------
__global__ __launch_bounds__(256) void k_detect(const unsigned* __restrict__ w,
                                                int* __restrict__ flag) {
  __shared__ int cnt;
  if (threadIdx.x == 0) cnt = 0;
  __syncthreads();
  int c = 0;
  for (int i = threadIdx.x; i < 4096; i += 256) {
    unsigned lo = w[i] & 0xFFFFu;
    if (lo - 0x3A00u < 0x600u) c++;  // [0x3A00, 0x4000): bf16 of [~5e-4, 1)
  }
  atomicAdd(&cnt, c);
  __syncthreads();
  if (threadIdx.x == 0) *flag = (cnt > 2048) ? 1 : 0;  // 1 = inputs are bf16
}

// ---------------- convert all float inputs to canonical fp32 ---------------
#define NCVT 23
struct Cvt {
  const void* src[NCVT];
  float* dst[NCVT];
  int n[NCVT];
};

__global__ __launch_bounds__(256) void k_convert(Cvt c, const int* __restrict__ flag) {
  const int f = *flag;
  const int stride = gridDim.x * blockDim.x;
  const int tid = blockIdx.x * blockDim.x + threadIdx.x;
#pragma unroll 1
  for (int a = 0; a < NCVT; a++) {
    const int n = c.n[a];
    const float* sf = (const float*)c.src[a];
    const unsigned short* sb = (const unsigned short*)c.src[a];
    float* d = c.dst[a];
    for (int i = tid; i < n; i += stride) d[i] = f ? b2f(sb[i]) : sf[i];
  }
}

// ---------------- CSR by src: hist -> scan -> scatter ----------------------
__global__ __launch_bounds__(256) void k_hist(const int* __restrict__ ei,
                                              int* __restrict__ cnt) {
  int e = blockIdx.x * 256 + threadIdx.x;
  if (e < EE) atomicAdd(cnt + ei[e], 1);
}

__global__ __launch_bounds__(256) void k_scan(const int* __restrict__ cnt,
                                              int* __restrict__ eptr,
                                              int* __restrict__ cursor) {
  __shared__ int part[256];
  const int t = threadIdx.x;
  const int c0 = t * 40;  // 250*40 = 10000
  int s = 0;
  for (int i = 0; i < 40; i++) {
    int idx = c0 + i;
    if (idx < NN) s += cnt[idx];
  }
  part[t] = s;
  __syncthreads();
  if (t == 0) {
    int run = 0;
    for (int i = 0; i < 256; i++) { int v = part[i]; part[i] = run; run += v; }
  }
  __syncthreads();
  int run = part[t];
  for (int i = 0; i < 40; i++) {
    int idx = c0 + i;
    if (idx < NN) {
      eptr[idx] = run;
      cursor[idx] = run;
      run += cnt[idx];
    }
  }
  if (t == 255) eptr[NN] = EE;
}

__global__ __launch_bounds__(256) void k_scatter(const int* __restrict__ ei,
                                                 int* __restrict__ cursor,
                                                 int* __restrict__ eord) {
  int e = blockIdx.x * 256 + threadIdx.x;
  if (e < EE) {
    int pos = atomicAdd(cursor + ei[e], 1);
    eord[pos] = e;
  }
}

// ---------------- feature lift: x = silu(x_in @ fl_W.T + fl_b) -------------
__global__ __launch_bounds__(256) void k_lift(const float* __restrict__ xin,
                                              const float* __restrict__ flW,
                                              const float* __restrict__ flb,
                                              float* __restrict__ x,
                                              unsigned short* __restrict__ xb) {
  int node = blockIdx.x * 4 + (threadIdx.x >> 6);
  int h = threadIdx.x & 63;
  float acc = flb[h];
#pragma unroll
  for (int c = 0; c < 11; c++)
    acc += xin[node * 11 + c] * flW[h * 11 + c];
  float v = siluf(acc);
  x[node * 64 + h] = v;
  xb[node * 64 + h] = f2b(v);
}

// ---------- s[e,k] = silu(ef @ nn_W1.T + nn_b1) bf16, deg atomic -----------
__global__ __launch_bounds__(128) void k_sdeg(const float* __restrict__ ea,
                                              const float* __restrict__ pos,
                                              const int* __restrict__ ei,
                                              const float* __restrict__ W1,
                                              const float* __restrict__ b1,
                                              unsigned short* __restrict__ s_bf,
                                              float* __restrict__ deg) {
  int e = blockIdx.x;
  int k = threadIdx.x;
  int src = ei[e], dst = ei[EE + e];
  float dx = pos[src * 3 + 0] - pos[dst * 3 + 0];
  float dy = pos[src * 3 + 1] - pos[dst * 3 + 1];
  float dz = pos[src * 3 + 2] - pos[dst * 3 + 2];
  float dist = sqrtf(dx * dx + dy * dy + dz * dz);
  float acc = b1[k];
  acc += ea[e * 4 + 0] * W1[k * 5 + 0];
  acc += ea[e * 4 + 1] * W1[k * 5 + 1];
  acc += ea[e * 4 + 2] * W1[k * 5 + 2];
  acc += ea[e * 4 + 3] * W1[k * 5 + 3];
  acc += dist * W1[k * 5 + 4];
  s_bf[e * 128 + k] = f2b(siluf(acc));
  if (k == 0) atomicAdd(deg + dst, 1.0f);
}

__global__ __launch_bounds__(256) void k_invdeg(const float* __restrict__ deg,
                                                float* __restrict__ inv) {
  int n = blockIdx.x * 256 + threadIdx.x;
  if (n < NN) inv[n] = 1.0f / fmaxf(deg[n], 1.0f);
}

// ---- W2t[(o*128+k)*64 + i] = bf16(W2[(i*64+o)*128 + k])  (1MB, once) ------
__global__ __launch_bounds__(256) void k_w2t(const float* __restrict__ W2,
                                             unsigned short* __restrict__ W2t) {
  int j = blockIdx.x * 256 + threadIdx.x;  // 64*128*64
  int i = j & 63;
  int k = (j >> 6) & 127;
  int o = j >> 13;
  W2t[j] = f2b(W2[(size_t)(i * 64 + o) * 128 + k]);
}

// ---- xb2[n,o] = sum_i x[n,i] * b2[i*64+o] ---------------------------------
__global__ __launch_bounds__(256) void k_xb2(const float* __restrict__ x,
                                             const float* __restrict__ b2,
                                             float* __restrict__ xb2) {
  int node = blockIdx.x * 4 + (threadIdx.x >> 6);
  int o = threadIdx.x & 63;
  int xvi = __float_as_int(x[node * 64 + o]);  // lane's o doubles as i-slot
  float acc = 0.0f;
#pragma unroll 8
  for (int i = 0; i < 64; i++) {
    float xi = __int_as_float(__builtin_amdgcn_readlane(xvi, i));
    acc += xi * b2[i * 64 + o];
  }
  xb2[node * 64 + o] = acc;
}

// ---- T chunk GEMM: Tc[n][c] = sum_i xb[n,i]*W2t[(o*128+K0+c%KC)*64+i] -----
template <int KC>
__global__ __launch_bounds__(256) void k_T(const unsigned short* __restrict__ xb,
                                           const unsigned short* __restrict__ W2t,
                                           unsigned short* __restrict__ Tc, int K0) {
  __shared__ unsigned short As[128 * 72];  // [node][i]
  __shared__ unsigned short Bs[128 * 72];  // [c_local][i]
  const int t = threadIdx.x;
  const int n0 = blockIdx.x * 128;
  const int c0 = blockIdx.y * 128;
  const int lane = t & 63;
  const int w = t >> 6;
  const int lm = lane & 15;
  const int quad = lane >> 4;
  const int wm = w & 1;
  const int wn = w >> 1;

  for (int p = t; p < 128 * 8; p += 256) {
    int r = p >> 3, cc = (p & 7) * 8;
    uint4 v = make_uint4(0u, 0u, 0u, 0u);
    if (n0 + r < NN) v = *reinterpret_cast<const uint4*>(xb + (size_t)(n0 + r) * 64 + cc);
    *reinterpret_cast<uint4*>(&As[r * 72 + cc]) = v;
  }
  for (int p = t; p < 128 * 8; p += 256) {
    int r = p >> 3, cc = (p & 7) * 8;
    int c = c0 + r;
    int o = c / KC;
    int kg = K0 + (c % KC);
    uint4 v = *reinterpret_cast<const uint4*>(W2t + (size_t)(o * 128 + kg) * 64 + cc);
    *reinterpret_cast<uint4*>(&Bs[r * 72 + cc]) = v;
  }
  __syncthreads();

  f32x4 acc[4][4];
#pragma unroll
  for (int mt = 0; mt < 4; mt++)
#pragma unroll
    for (int nt = 0; nt < 4; nt++) acc[mt][nt] = (f32x4)(0.0f);

#pragma unroll
  for (int ks = 0; ks < 2; ks++) {
    const int kk = ks * 32 + quad * 8;
    short8 af[4], bfr[4];
#pragma unroll
    for (int mt = 0; mt < 4; mt++)
      af[mt] = *reinterpret_cast<const short8*>(&As[(wm * 64 + mt * 16 + lm) * 72 + kk]);
#pragma unroll
    for (int nt = 0; nt < 4; nt++)
      bfr[nt] = *reinterpret_cast<const short8*>(&Bs[(wn * 64 + nt * 16 + lm) * 72 + kk]);
#pragma unroll
    for (int mt = 0; mt < 4; mt++)
#pragma unroll
      for (int nt = 0; nt < 4; nt++)
        acc[mt][nt] = __builtin_amdgcn_mfma_f32_16x16x32_bf16(af[mt], bfr[nt], acc[mt][nt], 0, 0, 0);
  }

#pragma unroll
  for (int nt = 0; nt < 4; nt++) {
    int c = c0 + wn * 64 + nt * 16 + lm;
#pragma unroll
    for (int mt = 0; mt < 4; mt++) {
#pragma unroll
      for (int reg = 0; reg < 4; reg++) {
        int n = n0 + wm * 64 + mt * 16 + quad * 4 + reg;
        if (n < NN) Tc[(size_t)n * (64 * KC) + c] = f2b(acc[mt][nt][reg]);
      }
    }
  }
}

// ---- grouped edge pass (KC=128 only): block n, lane=o ---------------------
// T row in VGPRs; per edge: s lane-distributed + readlane broadcast;
// agg[dst,o] += dot + xb2[n,o]  (direct atomic, no m buffer)
__global__ __launch_bounds__(64) void k_group(const unsigned short* __restrict__ Tc,
                                              const unsigned short* __restrict__ s_bf,
                                              const float* __restrict__ xb2,
                                              const int* __restrict__ ei,
                                              const int* __restrict__ eptr,
                                              const int* __restrict__ eord,
                                              float* __restrict__ agg) {
  const int n = blockIdx.x;
  const int lane = threadIdx.x;
  const int beg = eptr[n], end = eptr[n + 1];
  if (beg == end) return;
  // lane o holds T[n, o, 0:128] as 64 packed-bf16 dwords
  const uint4* trow = reinterpret_cast<const uint4*>(Tc + (size_t)n * 8192 + (size_t)lane * 128);
  unsigned tw[64];
#pragma unroll
  for (int j = 0; j < 16; j++) {
    uint4 v = trow[j];
    tw[4 * j + 0] = v.x; tw[4 * j + 1] = v.y;
    tw[4 * j + 2] = v.z; tw[4 * j + 3] = v.w;
  }
  const float xbv = xb2[(size_t)n * 64 + lane];
  for (int j = beg; j < end; j++) {
    int e = eord[j];
    int dst = ei[EE + e];
    int sw = ((const int*)(s_bf + (size_t)e * 128))[lane];  // lane l: s[2l],s[2l+1]
    float acc = 0.0f;
#pragma unroll
    for (int q = 0; q < 64; q++) {
      unsigned sq = (unsigned)__builtin_amdgcn_readlane(sw, q);
      acc += b2f_lo(sq) * b2f_lo(tw[q]) + b2f_hi(sq) * b2f_hi(tw[q]);
    }
    atomicAdd(agg + (size_t)dst * 64 + lane, acc + xbv);
  }
}

// ---- fallback per-edge chunk dot (KC<128) ---------------------------------
template <int KC>
__global__ __launch_bounds__(256) void k_emsg(const unsigned short* __restrict__ Tc,
                                              const unsigned short* __restrict__ s_bf,
                                              const int* __restrict__ ei,
                                              float* __restrict__ m, int K0, int first) {
  int e = blockIdx.x * 4 + (threadIdx.x >> 6);
  int o = threadIdx.x & 63;
  int src = ei[e];
  const uint4* tv = reinterpret_cast<const uint4*>(Tc + ((size_t)src * 64 + o) * KC);
  const uint4* sv = reinterpret_cast<const uint4*>(s_bf + (size_t)e * 128 + K0);
  float acc = 0.0f;
#pragma unroll
  for (int j = 0; j < KC / 8; j++) {
    uint4 a = tv[j], b = sv[j];
    unsigned aa[4] = {a.x, a.y, a.z, a.w};
    unsigned bb[4] = {b.x, b.y, b.z, b.w};
#pragma unroll
    for (int q = 0; q < 4; q++)
      acc += b2f_lo(aa[q]) * b2f_lo(bb[q]) + b2f_hi(aa[q]) * b2f_hi(bb[q]);
  }
  float* mp = m + (size_t)e * 64 + o;
  if (first) *mp = acc;
  else *mp += acc;
}

__global__ __launch_bounds__(256) void k_aggm(const float* __restrict__ m,
                                              const float* __restrict__ xb2,
                                              const int* __restrict__ ei,
                                              float* __restrict__ agg) {
  int e = blockIdx.x * 4 + (threadIdx.x >> 6);
  int o = threadIdx.x & 63;
  int src = ei[e], dst = ei[EE + e];
  atomicAdd(agg + (size_t)dst * 64 + o, m[(size_t)e * 64 + o] + xb2[(size_t)src * 64 + o]);
}

// -------- xc = silu(x @ root_W.T + root_b + agg*inv_deg) -------------------
__global__ __launch_bounds__(256) void k_xc(const float* __restrict__ x,
                                            const float* __restrict__ agg,
                                            const float* __restrict__ invd,
                                            const float* __restrict__ rootW,
                                            const float* __restrict__ rootb,
                                            float* __restrict__ xc) {
  __shared__ float At[64 * 34];
  __shared__ float Bt[64 * 68];
  const int t = threadIdx.x;
  const int n0 = blockIdx.x * 32;
  for (int p = t; p < 32 * 64; p += 256) {
    int n = p >> 6, k = p & 63;
    At[k * 34 + n] = (n0 + n < NN) ? x[(n0 + n) * 64 + k] : 0.0f;
  }
  for (int p = t; p < 64 * 64; p += 256) {
    int o = p >> 6, k = p & 63;
    Bt[k * 68 + o] = rootW[p];
  }
  __syncthreads();
  const int tn = t >> 4, to = t & 15;
  float acc[2][4] = {{0, 0, 0, 0}, {0, 0, 0, 0}};
  for (int k = 0; k < 64; k++) {
    f32x2 a = *reinterpret_cast<const f32x2*>(&At[k * 34 + tn * 2]);
    f32x4 b = *reinterpret_cast<const f32x4*>(&Bt[k * 68 + to * 4]);
#pragma unroll
    for (int j = 0; j < 4; j++) {
      acc[0][j] += a[0] * b[j];
      acc[1][j] += a[1] * b[j];
    }
  }
#pragma unroll
  for (int nn = 0; nn < 2; nn++) {
    int n = n0 + tn * 2 + nn;
    if (n < NN) {
      float idv = invd[n];
      f32x4 outv;
#pragma unroll
      for (int j = 0; j < 4; j++) {
        int o = to * 4 + j;
        float v = acc[nn][j] + rootb[o] + agg[(size_t)n * 64 + o] * idv;
        outv[j] = siluf(v);
      }
      *reinterpret_cast<f32x4*>(xc + n * 64 + to * 4) = outv;
    }
  }
}

// -------- fused GRU --------------------------------------------------------
__global__ __launch_bounds__(256) void k_gru(const float* __restrict__ xc,
                                             float* x, unsigned short* __restrict__ xb,
                                             const float* __restrict__ Wih,
                                             const float* __restrict__ Whh,
                                             const float* __restrict__ bih,
                                             const float* __restrict__ bhh) {
  __shared__ float At[64 * 34];
  __shared__ float Bt[64 * 200];
  const int t = threadIdx.x;
  const int n0 = blockIdx.x * 32;
  const int tn = t >> 4, to = t & 15;

  for (int p = t; p < 32 * 64; p += 256) {
    int n = p >> 6, k = p & 63;
    At[k * 34 + n] = (n0 + n < NN) ? xc[(n0 + n) * 64 + k] : 0.0f;
  }
  for (int p = t; p < 192 * 64; p += 256) {
    int o = p >> 6, k = p & 63;
    Bt[k * 200 + o] = Wih[p];
  }
  __syncthreads();
  float ai[2][3][4], ah[2][3][4];
#pragma unroll
  for (int j = 0; j < 3; j++)
#pragma unroll
    for (int hh = 0; hh < 4; hh++) {
      float bv = bih[j * 64 + to * 4 + hh];
      ai[0][j][hh] = bv; ai[1][j][hh] = bv;
      float bv2 = bhh[j * 64 + to * 4 + hh];
      ah[0][j][hh] = bv2; ah[1][j][hh] = bv2;
    }
  for (int k = 0; k < 64; k++) {
    f32x2 a = *reinterpret_cast<const f32x2*>(&At[k * 34 + tn * 2]);
#pragma unroll
    for (int j = 0; j < 3; j++) {
      f32x4 b = *reinterpret_cast<const f32x4*>(&Bt[k * 200 + j * 64 + to * 4]);
#pragma unroll
      for (int hh = 0; hh < 4; hh++) {
        ai[0][j][hh] += a[0] * b[hh];
        ai[1][j][hh] += a[1] * b[hh];
      }
    }
  }
  __syncthreads();
  for (int p = t; p < 32 * 64; p += 256) {
    int n = p >> 6, k = p & 63;
    At[k * 34 + n] = (n0 + n < NN) ? x[(n0 + n) * 64 + k] : 0.0f;
  }
  for (int p = t; p < 192 * 64; p += 256) {
    int o = p >> 6, k = p & 63;
    Bt[k * 200 + o] = Whh[p];
  }
  __syncthreads();
  for (int k = 0; k < 64; k++) {
    f32x2 a = *reinterpret_cast<const f32x2*>(&At[k * 34 + tn * 2]);
#pragma unroll
    for (int j = 0; j < 3; j++) {
      f32x4 b = *reinterpret_cast<const f32x4*>(&Bt[k * 200 + j * 64 + to * 4]);
#pragma unroll
      for (int hh = 0; hh < 4; hh++) {
        ah[0][j][hh] += a[0] * b[hh];
        ah[1][j][hh] += a[1] * b[hh];
      }
    }
  }
#pragma unroll
  for (int nn = 0; nn < 2; nn++) {
    int n = n0 + tn * 2 + nn;
    if (n < NN) {
      f32x4 xn;
#pragma unroll
      for (int hh = 0; hh < 4; hh++) {
        float r = sigm(ai[nn][0][hh] + ah[nn][0][hh]);
        float z = sigm(ai[nn][1][hh] + ah[nn][1][hh]);
        float ng = tanhf(ai[nn][2][hh] + r * ah[nn][2][hh]);
        float hold = At[(to * 4 + hh) * 34 + tn * 2 + nn];
        xn[hh] = (1.0f - z) * ng + z * hold;
      }
      *reinterpret_cast<f32x4*>(x + n * 64 + to * 4) = xn;
      unsigned p0 = (unsigned)f2b(xn[0]) | ((unsigned)f2b(xn[1]) << 16);
      unsigned p1 = (unsigned)f2b(xn[2]) | ((unsigned)f2b(xn[3]) << 16);
      *reinterpret_cast<uint2*>(xb + (size_t)n * 64 + to * 4) = make_uint2(p0, p1);
    }
  }
}

// ------------------------------- Set2Set -----------------------------------
__global__ __launch_bounds__(64) void k_lstm(const float* __restrict__ qs,
                                             const float* __restrict__ Wih,
                                             const float* __restrict__ Whh,
                                             const float* __restrict__ bih,
                                             const float* __restrict__ bhh,
                                             float* hl, float* cl) {
  int b = blockIdx.x, lane = threadIdx.x;
  float g[4];
#pragma unroll
  for (int j = 0; j < 4; j++) {
    int row = j * 64 + lane;
    float acc = bih[row] + bhh[row];
    for (int k = 0; k < 128; k++) acc += qs[b * 128 + k] * Wih[row * 128 + k];
    for (int k = 0; k < 64; k++) acc += hl[b * 64 + k] * Whh[row * 64 + k];
    g[j] = acc;
  }
  float ig = sigm(g[0]), fg = sigm(g[1]), gg = tanhf(g[2]), og = sigm(g[3]);
  float c = fg * cl[b * 64 + lane] + ig * gg;
  cl[b * 64 + lane] = c;
  hl[b * 64 + lane] = og * tanhf(c);
}

__global__ __launch_bounds__(256) void k_edot(const float* __restrict__ x,
                                              const float* __restrict__ hl,
                                              const int* __restrict__ batch,
                                              float* __restrict__ e_buf,
                                              unsigned* __restrict__ mmax) {
  int node = blockIdx.x * 4 + (threadIdx.x >> 6);
  int lane = threadIdx.x & 63;
  int b = batch[node];
  float v = x[node * 64 + lane] * hl[b * 64 + lane];
#pragma unroll
  for (int mm = 32; mm; mm >>= 1) v += __shfl_xor(v, mm, 64);
  if (lane == 0) {
    e_buf[node] = v;
    atomicMax(mmax + b, encf(v));
  }
}

__global__ __launch_bounds__(256) void k_asum(const float* __restrict__ e_buf,
                                              const int* __restrict__ batch,
                                              const unsigned* __restrict__ mmax,
                                              float* __restrict__ a_buf,
                                              float* __restrict__ asum) {
  int n = blockIdx.x * 256 + threadIdx.x;
  if (n < NN) {
    int b = batch[n];
    unsigned u = mmax[b];
    float ev = e_buf[n];
    float mx = (u == 0u) ? ev : decf(u);  // safety: untouched slot -> a=1
    float a = __expf(ev - mx);
    a_buf[n] = a;
    atomicAdd(asum + b, a);
  }
}

__global__ __launch_bounds__(256) void k_rread(const float* __restrict__ x,
                                               const int* __restrict__ batch,
                                               const float* __restrict__ a_buf,
                                               const float* __restrict__ asum,
                                               float* __restrict__ rr) {
  int node = blockIdx.x * 4 + (threadIdx.x >> 6);
  int lane = threadIdx.x & 63;
  int b = batch[node];
  float wgt = a_buf[node] / asum[b];
  atomicAdd(rr + (size_t)b * 64 + lane, wgt * x[node * 64 + lane]);
}

__global__ __launch_bounds__(64) void k_qstar(const float* __restrict__ hl,
                                              const float* __restrict__ rr,
                                              float* __restrict__ qs) {
  int b = blockIdx.x, lane = threadIdx.x;
  qs[b * 128 + lane] = hl[b * 64 + lane];
  qs[b * 128 + 64 + lane] = rr[b * 64 + lane];
}

__global__ __launch_bounds__(64) void k_out(const float* __restrict__ qs,
                                            const float* __restrict__ W1,
                                            const float* __restrict__ b1,
                                            const float* __restrict__ W2,
                                            const float* __restrict__ b2o,
                                            void* __restrict__ out,
                                            const int* __restrict__ flag) {
  int b = blockIdx.x, lane = threadIdx.x;
  float acc = b1[lane];
  for (int k = 0; k < 128; k++) acc += qs[b * 128 + k] * W1[lane * 128 + k];
  float u = siluf(acc) * W2[lane];
#pragma unroll
  for (int mm = 32; mm; mm >>= 1) u += __shfl_xor(u, mm, 64);
  if (lane == 0) {
    float v = u + b2o[0];
    if (*flag) ((unsigned short*)out)[b] = f2b(v);
    else ((float*)out)[b] = v;
  }
}

// ---------------------------------------------------------------------------
template <int KC>
static void run_chunks(const unsigned short* xb, const unsigned short* W2t,
                       unsigned short* Tc, const unsigned short* s_bf,
                       const int* ei, float* m, hipStream_t stream) {
  const int nch = 128 / KC;
  for (int c = 0; c < nch; c++) {
    k_T<KC><<<dim3((NN + 127) / 128, (64 * KC) / 128), 256, 0, stream>>>(xb, W2t, Tc, c * KC);
    k_emsg<KC><<<EE / 4, 256, 0, stream>>>(Tc, s_bf, ei, m, c * KC, c == 0 ? 1 : 0);
  }
}

extern "C" void kernel_launch(void* const* d_in, const int* in_sizes, int n_in,
                              void* d_out, int out_size, void* d_ws, size_t ws_size,
                              hipStream_t stream) {
  (void)n_in; (void)out_size;
  const bool sig_order = (in_sizes[1] == 2 * EE);
  const void* p_x   = d_in[0];
  const void* p_ea  = sig_order ? d_in[2] : d_in[1];
  const void* p_pos = sig_order ? d_in[3] : d_in[2];
  const int* edge_index = (const int*)(sig_order ? d_in[1] : d_in[3]);
  const int* batch      = (const int*)d_in[4];
  const void* p_w[20];
  for (int i = 0; i < 20; i++) p_w[i] = d_in[5 + i];

  char* base = (char*)d_ws;
  size_t off = 0;
  auto alloc = [&](size_t bytes) -> char* {
    char* p = base + off;
    off = (off + bytes + 255) & ~(size_t)255;
    return p;
  };
  int* flag = (int*)alloc(4);
  static const int cvt_n[NCVT] = {
      NN * 11, EE * 4, NN * 3,
      64 * 11, 64, 128 * 5, 128, 4096 * 128, 4096,
      64 * 64, 64,
      192 * 64, 192 * 64, 192, 192,
      256 * 128, 256 * 64, 256, 256,
      64 * 128, 64, 64, 1};
  float* canon[NCVT];
  for (int i = 0; i < NCVT; i++) canon[i] = (float*)alloc((size_t)cvt_n[i] * 4);
  const float* c_x    = canon[0];
  const float* c_ea   = canon[1];
  const float* c_pos  = canon[2];
  const float* c_flW  = canon[3];
  const float* c_flb  = canon[4];
  const float* c_W1   = canon[5];
  const float* c_b1   = canon[6];
  const float* c_W2   = canon[7];
  const float* c_b2   = canon[8];
  const float* c_rW   = canon[9];
  const float* c_rb   = canon[10];
  const float* c_gWih = canon[11];
  const float* c_gWhh = canon[12];
  const float* c_gbih = canon[13];
  const float* c_gbhh = canon[14];
  const float* c_lWih = canon[15];
  const float* c_lWhh = canon[16];
  const float* c_lbih = canon[17];
  const float* c_lbhh = canon[18];
  const float* c_oW1  = canon[19];
  const float* c_ob1  = canon[20];
  const float* c_oW2  = canon[21];
  const float* c_ob2  = canon[22];

  unsigned short* s_bf = (unsigned short*)alloc((size_t)EE * 128 * 2);  // 12.8MB
  float* m    = (float*)alloc((size_t)EE * 64 * 4);                     // 12.8MB (fallback only)
  float* x    = (float*)alloc((size_t)NN * 64 * 4);
  unsigned short* xb = (unsigned short*)alloc((size_t)NN * 64 * 2);
  float* xc   = (float*)alloc((size_t)NN * 64 * 4);
  float* agg  = (float*)alloc((size_t)NN * 64 * 4);
  float* xb2  = (float*)alloc((size_t)NN * 64 * 4);
  unsigned short* W2t = (unsigned short*)alloc((size_t)4096 * 128 * 2); // 1MB
  float* deg  = (float*)alloc((size_t)NN * 4);
  float* invd = (float*)alloc((size_t)NN * 4);
  int* cnt    = (int*)alloc((size_t)NN * 4);
  int* eptr   = (int*)alloc((size_t)(NN + 1) * 4);
  int* cursor = (int*)alloc((size_t)NN * 4);
  int* eord   = (int*)alloc((size_t)EE * 4);
  float* hl   = (float*)alloc((size_t)BBG * 64 * 4);   // hl,cl,qs contiguous
  float* cl   = (float*)alloc((size_t)BBG * 64 * 4);
  float* qs   = (float*)alloc((size_t)BBG * 128 * 4);
  unsigned* mmax = (unsigned*)alloc((size_t)BBG * 4);  // mmax,asum,rr contiguous
  float* asum = (float*)alloc((size_t)BBG * 4);
  float* rr   = (float*)alloc((size_t)BBG * 64 * 4);
  float* e_buf = (float*)alloc((size_t)NN * 4);
  float* a_buf = (float*)alloc((size_t)NN * 4);
  size_t base_need = off;

  int KC = 0;
  const int kcs[5] = {128, 64, 32, 16, 8};
  for (int i = 0; i < 5; i++) {
    size_t need = base_need + (size_t)NN * 64 * kcs[i] * 2 + 256;
    if (need <= ws_size) { KC = kcs[i]; break; }
  }
  if (KC == 0) return;
  unsigned short* Tc = (unsigned short*)alloc((size_t)NN * 64 * KC * 2);

  // ---- dtype detect + convert ----
  k_detect<<<1, 256, 0, stream>>>((const unsigned*)p_ea, flag);
  Cvt cvt;
  cvt.src[0] = p_x; cvt.src[1] = p_ea; cvt.src[2] = p_pos;
  for (int i = 0; i < 20; i++) cvt.src[3 + i] = p_w[i];
  for (int i = 0; i < NCVT; i++) { cvt.dst[i] = canon[i]; cvt.n[i] = cvt_n[i]; }
  k_convert<<<512, 256, 0, stream>>>(cvt, flag);

  // ---- prologue ----
  hipMemsetAsync(deg, 0, (size_t)NN * 4, stream);
  hipMemsetAsync(cnt, 0, (size_t)NN * 4, stream);
  k_lift<<<NN / 4, 256, 0, stream>>>(c_x, c_flW, c_flb, x, xb);
  k_sdeg<<<EE, 128, 0, stream>>>(c_ea, c_pos, edge_index, c_W1, c_b1, s_bf, deg);
  k_invdeg<<<(NN + 255) / 256, 256, 0, stream>>>(deg, invd);
  k_w2t<<<(4096 * 128) / 256, 256, 0, stream>>>(c_W2, W2t);
  // CSR by src (once; reused all layers)
  k_hist<<<(EE + 255) / 256, 256, 0, stream>>>(edge_index, cnt);
  k_scan<<<1, 256, 0, stream>>>(cnt, eptr, cursor);
  k_scatter<<<(EE + 255) / 256, 256, 0, stream>>>(edge_index, cursor, eord);

  // ---- 4 message-passing layers ----
  for (int layer = 0; layer < 4; layer++) {
    hipMemsetAsync(agg, 0, (size_t)NN * 64 * 4, stream);
    k_xb2<<<NN / 4, 256, 0, stream>>>(x, c_b2, xb2);
    if (KC == 128) {
      k_T<128><<<dim3((NN + 127) / 128, 64), 256, 0, stream>>>(xb, W2t, Tc, 0);
      k_group<<<NN, 64, 0, stream>>>(Tc, s_bf, xb2, edge_index, eptr, eord, agg);
    } else {
      switch (KC) {
        case 64: run_chunks<64>(xb, W2t, Tc, s_bf, edge_index, m, stream); break;
        case 32: run_chunks<32>(xb, W2t, Tc, s_bf, edge_index, m, stream); break;
        case 16: run_chunks<16>(xb, W2t, Tc, s_bf, edge_index, m, stream); break;
        default: run_chunks<8>(xb, W2t, Tc, s_bf, edge_index, m, stream); break;
      }
      k_aggm<<<EE / 4, 256, 0, stream>>>(m, xb2, edge_index, agg);
    }
    k_xc<<<(NN + 31) / 32, 256, 0, stream>>>(x, agg, invd, c_rW, c_rb, xc);
    k_gru<<<(NN + 31) / 32, 256, 0, stream>>>(xc, x, xb, c_gWih, c_gWhh, c_gbih, c_gbhh);
  }

  // ---- Set2Set ----
  hipMemsetAsync(hl, 0, (size_t)(BBG * 64 + BBG * 64 + BBG * 128) * 4, stream);
  for (int step = 0; step < 3; step++) {
    hipMemsetAsync(mmax, 0, (size_t)(BBG + BBG + BBG * 64) * 4, stream);
    k_lstm<<<BBG, 64, 0, stream>>>(qs, c_lWih, c_lWhh, c_lbih, c_lbhh, hl, cl);
    k_edot<<<NN / 4, 256, 0, stream>>>(x, hl, batch, e_buf, mmax);
    k_asum<<<(NN + 255) / 256, 256, 0, stream>>>(e_buf, batch, mmax, a_buf, asum);
    k_rread<<<NN / 4, 256, 0, stream>>>(x, batch, a_buf, asum, rr);
    k_qstar<<<BBG, 64, 0, stream>>>(hl, rr, qs);
  }

  // ---- output head ----
  k_out<<<BBG, 64, 0, stream>>>(qs, c_oW1, c_ob1, c_oW2, c_ob2, d_out, flag);
}

// Round 5
// 925.320 us; speedup vs baseline: 1.6138x; 1.1055x over previous
//
#include <hip/hip_runtime.h>
#include <stdint.h>

// ---------------------------------------------------------------------------
// SpatialGNN forward, round 5.
// R4: 1023us, k_T store-bound with 1.7x write amplification (280MB vs 164MB
// logical: 2B scattered bf16 stores -> partial cachelines).
// R5: (a) k_T epilogue stages C tile in LDS then writes fully-coalesced
// 256B-per-16-lanes rows (full lines only); (b) launch-count diet: fold
// agg-zero into k_xb2, fold qstar/memsets/first-init into k_lstm, fold
// invdeg into k_scan (dst histogram in k_hist), drop k_qstar/k_invdeg.
// ---------------------------------------------------------------------------

#define NN 10000
#define EE 50000
#define BBG 512

typedef __attribute__((ext_vector_type(8))) short short8;
typedef __attribute__((ext_vector_type(4))) float f32x4;
typedef __attribute__((ext_vector_type(2))) float f32x2;

__device__ __forceinline__ float b2f(unsigned short u) {
  return __uint_as_float(((unsigned)u) << 16);
}
__device__ __forceinline__ float b2f_lo(unsigned u) { return __uint_as_float(u << 16); }
__device__ __forceinline__ float b2f_hi(unsigned u) { return __uint_as_float(u & 0xFFFF0000u); }
__device__ __forceinline__ unsigned short f2b(float f) {
  unsigned u = __float_as_uint(f);
  u += 0x7FFFu + ((u >> 16) & 1u);  // RNE
  return (unsigned short)(u >> 16);
}
__device__ __forceinline__ float sigm(float x) { return 1.0f / (1.0f + __expf(-x)); }
__device__ __forceinline__ float siluf(float x) { return x / (1.0f + __expf(-x)); }

__device__ __forceinline__ unsigned encf(float f) {  // monotone float->uint
  unsigned u = __float_as_uint(f);
  return (u & 0x80000000u) ? ~u : (u | 0x80000000u);
}
__device__ __forceinline__ float decf(unsigned u) {
  unsigned b = (u & 0x80000000u) ? (u & 0x7FFFFFFFu) : ~u;
  return __uint_as_float(b);
}

// ---------------- dtype detection on edge_attr (uniform[0,1)) --------------
__global__ __launch_bounds__(256) void k_detect(const unsigned* __restrict__ w,
                                                int* __restrict__ flag) {
  __shared__ int cnt;
  if (threadIdx.x == 0) cnt = 0;
  __syncthreads();
  int c = 0;
  for (int i = threadIdx.x; i < 4096; i += 256) {
    unsigned lo = w[i] & 0xFFFFu;
    if (lo - 0x3A00u < 0x600u) c++;  // [0x3A00, 0x4000): bf16 of [~5e-4, 1)
  }
  atomicAdd(&cnt, c);
  __syncthreads();
  if (threadIdx.x == 0) *flag = (cnt > 2048) ? 1 : 0;  // 1 = inputs are bf16
}

// ---------------- convert all float inputs to canonical fp32 ---------------
#define NCVT 23
struct Cvt {
  const void* src[NCVT];
  float* dst[NCVT];
  int n[NCVT];
};

__global__ __launch_bounds__(256) void k_convert(Cvt c, const int* __restrict__ flag) {
  const int f = *flag;
  const int stride = gridDim.x * blockDim.x;
  const int tid = blockIdx.x * blockDim.x + threadIdx.x;
#pragma unroll 1
  for (int a = 0; a < NCVT; a++) {
    const int n = c.n[a];
    const float* sf = (const float*)c.src[a];
    const unsigned short* sb = (const unsigned short*)c.src[a];
    float* d = c.dst[a];
    for (int i = tid; i < n; i += stride) d[i] = f ? b2f(sb[i]) : sf[i];
  }
}

// ---------------- CSR by src + dst degree histogram ------------------------
__global__ __launch_bounds__(256) void k_hist(const int* __restrict__ ei,
                                              int* __restrict__ cnt,
                                              int* __restrict__ cntd) {
  int e = blockIdx.x * 256 + threadIdx.x;
  if (e < EE) {
    atomicAdd(cnt + ei[e], 1);
    atomicAdd(cntd + ei[EE + e], 1);
  }
}

__global__ __launch_bounds__(256) void k_scan(const int* __restrict__ cnt,
                                              const int* __restrict__ cntd,
                                              int* __restrict__ eptr,
                                              int* __restrict__ cursor,
                                              float* __restrict__ invd) {
  __shared__ int part[256];
  const int t = threadIdx.x;
  const int c0 = t * 40;  // 250*40 = 10000
  int s = 0;
  for (int i = 0; i < 40; i++) {
    int idx = c0 + i;
    if (idx < NN) s += cnt[idx];
  }
  part[t] = s;
  __syncthreads();
  if (t == 0) {
    int run = 0;
    for (int i = 0; i < 256; i++) { int v = part[i]; part[i] = run; run += v; }
  }
  __syncthreads();
  int run = part[t];
  for (int i = 0; i < 40; i++) {
    int idx = c0 + i;
    if (idx < NN) {
      eptr[idx] = run;
      cursor[idx] = run;
      run += cnt[idx];
      invd[idx] = 1.0f / fmaxf((float)cntd[idx], 1.0f);
    }
  }
  if (t == 255) eptr[NN] = EE;
}

__global__ __launch_bounds__(256) void k_scatter(const int* __restrict__ ei,
                                                 int* __restrict__ cursor,
                                                 int* __restrict__ eord) {
  int e = blockIdx.x * 256 + threadIdx.x;
  if (e < EE) {
    int pos = atomicAdd(cursor + ei[e], 1);
    eord[pos] = e;
  }
}

// ---------------- feature lift: x = silu(x_in @ fl_W.T + fl_b) -------------
__global__ __launch_bounds__(256) void k_lift(const float* __restrict__ xin,
                                              const float* __restrict__ flW,
                                              const float* __restrict__ flb,
                                              float* __restrict__ x,
                                              unsigned short* __restrict__ xb) {
  int node = blockIdx.x * 4 + (threadIdx.x >> 6);
  int h = threadIdx.x & 63;
  float acc = flb[h];
#pragma unroll
  for (int c = 0; c < 11; c++)
    acc += xin[node * 11 + c] * flW[h * 11 + c];
  float v = siluf(acc);
  x[node * 64 + h] = v;
  xb[node * 64 + h] = f2b(v);
}

// ---------- s[e,k] = silu(ef @ nn_W1.T + nn_b1) bf16 -----------------------
__global__ __launch_bounds__(256) void k_sdeg(const float* __restrict__ ea,
                                              const float* __restrict__ pos,
                                              const int* __restrict__ ei,
                                              const float* __restrict__ W1,
                                              const float* __restrict__ b1,
                                              unsigned short* __restrict__ s_bf) {
  int e = blockIdx.x * 2 + (threadIdx.x >> 7);
  int k = threadIdx.x & 127;
  int src = ei[e], dst = ei[EE + e];
  float dx = pos[src * 3 + 0] - pos[dst * 3 + 0];
  float dy = pos[src * 3 + 1] - pos[dst * 3 + 1];
  float dz = pos[src * 3 + 2] - pos[dst * 3 + 2];
  float dist = sqrtf(dx * dx + dy * dy + dz * dz);
  float acc = b1[k];
  acc += ea[e * 4 + 0] * W1[k * 5 + 0];
  acc += ea[e * 4 + 1] * W1[k * 5 + 1];
  acc += ea[e * 4 + 2] * W1[k * 5 + 2];
  acc += ea[e * 4 + 3] * W1[k * 5 + 3];
  acc += dist * W1[k * 5 + 4];
  s_bf[e * 128 + k] = f2b(siluf(acc));
}

// ---- W2t[(o*128+k)*64 + i] = bf16(W2[(i*64+o)*128 + k])  (1MB, once) ------
__global__ __launch_bounds__(256) void k_w2t(const float* __restrict__ W2,
                                             unsigned short* __restrict__ W2t) {
  int j = blockIdx.x * 256 + threadIdx.x;  // 64*128*64
  int i = j & 63;
  int k = (j >> 6) & 127;
  int o = j >> 13;
  W2t[j] = f2b(W2[(size_t)(i * 64 + o) * 128 + k]);
}

// ---- xb2[n,o] = sum_i x[n,i] * b2[i*64+o]; also zero agg ------------------
__global__ __launch_bounds__(256) void k_xb2(const float* __restrict__ x,
                                             const float* __restrict__ b2,
                                             float* __restrict__ xb2,
                                             float* __restrict__ agg) {
  int node = blockIdx.x * 4 + (threadIdx.x >> 6);
  int o = threadIdx.x & 63;
  int xvi = __float_as_int(x[node * 64 + o]);  // lane's o doubles as i-slot
  float acc = 0.0f;
#pragma unroll 8
  for (int i = 0; i < 64; i++) {
    float xi = __int_as_float(__builtin_amdgcn_readlane(xvi, i));
    acc += xi * b2[i * 64 + o];
  }
  xb2[node * 64 + o] = acc;
  agg[(size_t)node * 64 + o] = 0.0f;
}

// ---- T chunk GEMM: Tc[n][c] = sum_i xb[n,i]*W2t[(o*128+K0+c%KC)*64+i] -----
// Epilogue: LDS-staged transpose -> fully coalesced 16B/lane stores.
template <int KC>
__global__ __launch_bounds__(256) void k_T(const unsigned short* __restrict__ xb,
                                           const unsigned short* __restrict__ W2t,
                                           unsigned short* __restrict__ Tc, int K0) {
  __shared__ unsigned short sh[2 * 128 * 72];  // As | Bs, reused as C staging
  unsigned short* As = sh;             // [node][i]
  unsigned short* Bs = sh + 128 * 72;  // [c_local][i]
  const int t = threadIdx.x;
  const int n0 = blockIdx.x * 128;
  const int c0 = blockIdx.y * 128;
  const int lane = t & 63;
  const int w = t >> 6;
  const int lm = lane & 15;
  const int quad = lane >> 4;
  const int wm = w & 1;
  const int wn = w >> 1;

  for (int p = t; p < 128 * 8; p += 256) {
    int r = p >> 3, cc = (p & 7) * 8;
    uint4 v = make_uint4(0u, 0u, 0u, 0u);
    if (n0 + r < NN) v = *reinterpret_cast<const uint4*>(xb + (size_t)(n0 + r) * 64 + cc);
    *reinterpret_cast<uint4*>(&As[r * 72 + cc]) = v;
  }
  for (int p = t; p < 128 * 8; p += 256) {
    int r = p >> 3, cc = (p & 7) * 8;
    int c = c0 + r;
    int o = c / KC;
    int kg = K0 + (c % KC);
    uint4 v = *reinterpret_cast<const uint4*>(W2t + (size_t)(o * 128 + kg) * 64 + cc);
    *reinterpret_cast<uint4*>(&Bs[r * 72 + cc]) = v;
  }
  __syncthreads();

  f32x4 acc[4][4];
#pragma unroll
  for (int mt = 0; mt < 4; mt++)
#pragma unroll
    for (int nt = 0; nt < 4; nt++) acc[mt][nt] = (f32x4)(0.0f);

#pragma unroll
  for (int ks = 0; ks < 2; ks++) {
    const int kk = ks * 32 + quad * 8;
    short8 af[4], bfr[4];
#pragma unroll
    for (int mt = 0; mt < 4; mt++)
      af[mt] = *reinterpret_cast<const short8*>(&As[(wm * 64 + mt * 16 + lm) * 72 + kk]);
#pragma unroll
    for (int nt = 0; nt < 4; nt++)
      bfr[nt] = *reinterpret_cast<const short8*>(&Bs[(wn * 64 + nt * 16 + lm) * 72 + kk]);
#pragma unroll
    for (int mt = 0; mt < 4; mt++)
#pragma unroll
      for (int nt = 0; nt < 4; nt++)
        acc[mt][nt] = __builtin_amdgcn_mfma_f32_16x16x32_bf16(af[mt], bfr[nt], acc[mt][nt], 0, 0, 0);
  }

  // ---- epilogue: stage to LDS [row][132], then coalesced row stores ----
  __syncthreads();
  unsigned short* st = sh;  // 128*132 = 16896 shorts <= 18432 avail
#pragma unroll
  for (int nt = 0; nt < 4; nt++) {
    int col = wn * 64 + nt * 16 + lm;
#pragma unroll
    for (int mt = 0; mt < 4; mt++) {
#pragma unroll
      for (int reg = 0; reg < 4; reg++) {
        int row = wm * 64 + mt * 16 + quad * 4 + reg;
        st[row * 132 + col] = f2b(acc[mt][nt][reg]);
      }
    }
  }
  __syncthreads();
  const int r16 = t >> 4;
  const int c8 = (t & 15) * 8;
#pragma unroll
  for (int it = 0; it < 8; it++) {
    int row = it * 16 + r16;
    int n = n0 + row;
    if (n < NN) {
      uint2 v0 = *reinterpret_cast<const uint2*>(&st[row * 132 + c8]);
      uint2 v1 = *reinterpret_cast<const uint2*>(&st[row * 132 + c8 + 4]);
      uint4 v = make_uint4(v0.x, v0.y, v1.x, v1.y);
      *reinterpret_cast<uint4*>(Tc + (size_t)n * (64 * KC) + c0 + c8) = v;
    }
  }
}

// ---- grouped edge pass (KC=128 only): block n, lane=o ---------------------
__global__ __launch_bounds__(64) void k_group(const unsigned short* __restrict__ Tc,
                                              const unsigned short* __restrict__ s_bf,
                                              const float* __restrict__ xb2,
                                              const int* __restrict__ ei,
                                              const int* __restrict__ eptr,
                                              const int* __restrict__ eord,
                                              float* __restrict__ agg) {
  const int n = blockIdx.x;
  const int lane = threadIdx.x;
  const int beg = eptr[n], end = eptr[n + 1];
  if (beg == end) return;
  const uint4* trow = reinterpret_cast<const uint4*>(Tc + (size_t)n * 8192 + (size_t)lane * 128);
  unsigned tw[64];
#pragma unroll
  for (int j = 0; j < 16; j++) {
    uint4 v = trow[j];
    tw[4 * j + 0] = v.x; tw[4 * j + 1] = v.y;
    tw[4 * j + 2] = v.z; tw[4 * j + 3] = v.w;
  }
  const float xbv = xb2[(size_t)n * 64 + lane];
  for (int j = beg; j < end; j++) {
    int e = eord[j];
    int dst = ei[EE + e];
    int sw = ((const int*)(s_bf + (size_t)e * 128))[lane];
    float acc = 0.0f;
#pragma unroll
    for (int q = 0; q < 64; q++) {
      unsigned sq = (unsigned)__builtin_amdgcn_readlane(sw, q);
      acc += b2f_lo(sq) * b2f_lo(tw[q]) + b2f_hi(sq) * b2f_hi(tw[q]);
    }
    atomicAdd(agg + (size_t)dst * 64 + lane, acc + xbv);
  }
}

// ---- fallback per-edge chunk dot (KC<128) ---------------------------------
template <int KC>
__global__ __launch_bounds__(256) void k_emsg(const unsigned short* __restrict__ Tc,
                                              const unsigned short* __restrict__ s_bf,
                                              const int* __restrict__ ei,
                                              float* __restrict__ m, int K0, int first) {
  int e = blockIdx.x * 4 + (threadIdx.x >> 6);
  int o = threadIdx.x & 63;
  int src = ei[e];
  const uint4* tv = reinterpret_cast<const uint4*>(Tc + ((size_t)src * 64 + o) * KC);
  const uint4* sv = reinterpret_cast<const uint4*>(s_bf + (size_t)e * 128 + K0);
  float acc = 0.0f;
#pragma unroll
  for (int j = 0; j < KC / 8; j++) {
    uint4 a = tv[j], b = sv[j];
    unsigned aa[4] = {a.x, a.y, a.z, a.w};
    unsigned bb[4] = {b.x, b.y, b.z, b.w};
#pragma unroll
    for (int q = 0; q < 4; q++)
      acc += b2f_lo(aa[q]) * b2f_lo(bb[q]) + b2f_hi(aa[q]) * b2f_hi(bb[q]);
  }
  float* mp = m + (size_t)e * 64 + o;
  if (first) *mp = acc;
  else *mp += acc;
}

__global__ __launch_bounds__(256) void k_aggm(const float* __restrict__ m,
                                              const float* __restrict__ xb2,
                                              const int* __restrict__ ei,
                                              float* __restrict__ agg) {
  int e = blockIdx.x * 4 + (threadIdx.x >> 6);
  int o = threadIdx.x & 63;
  int src = ei[e], dst = ei[EE + e];
  atomicAdd(agg + (size_t)dst * 64 + o, m[(size_t)e * 64 + o] + xb2[(size_t)src * 64 + o]);
}

// -------- xc = silu(x @ root_W.T + root_b + agg*inv_deg) -------------------
__global__ __launch_bounds__(256) void k_xc(const float* __restrict__ x,
                                            const float* __restrict__ agg,
                                            const float* __restrict__ invd,
                                            const float* __restrict__ rootW,
                                            const float* __restrict__ rootb,
                                            float* __restrict__ xc) {
  __shared__ float At[64 * 34];
  __shared__ float Bt[64 * 68];
  const int t = threadIdx.x;
  const int n0 = blockIdx.x * 32;
  for (int p = t; p < 32 * 64; p += 256) {
    int n = p >> 6, k = p & 63;
    At[k * 34 + n] = (n0 + n < NN) ? x[(n0 + n) * 64 + k] : 0.0f;
  }
  for (int p = t; p < 64 * 64; p += 256) {
    int o = p >> 6, k = p & 63;
    Bt[k * 68 + o] = rootW[p];
  }
  __syncthreads();
  const int tn = t >> 4, to = t & 15;
  float acc[2][4] = {{0, 0, 0, 0}, {0, 0, 0, 0}};
  for (int k = 0; k < 64; k++) {
    f32x2 a = *reinterpret_cast<const f32x2*>(&At[k * 34 + tn * 2]);
    f32x4 b = *reinterpret_cast<const f32x4*>(&Bt[k * 68 + to * 4]);
#pragma unroll
    for (int j = 0; j < 4; j++) {
      acc[0][j] += a[0] * b[j];
      acc[1][j] += a[1] * b[j];
    }
  }
#pragma unroll
  for (int nn = 0; nn < 2; nn++) {
    int n = n0 + tn * 2 + nn;
    if (n < NN) {
      float idv = invd[n];
      f32x4 outv;
#pragma unroll
      for (int j = 0; j < 4; j++) {
        int o = to * 4 + j;
        float v = acc[nn][j] + rootb[o] + agg[(size_t)n * 64 + o] * idv;
        outv[j] = siluf(v);
      }
      *reinterpret_cast<f32x4*>(xc + n * 64 + to * 4) = outv;
    }
  }
}

// -------- fused GRU --------------------------------------------------------
__global__ __launch_bounds__(256) void k_gru(const float* __restrict__ xc,
                                             float* x, unsigned short* __restrict__ xb,
                                             const float* __restrict__ Wih,
                                             const float* __restrict__ Whh,
                                             const float* __restrict__ bih,
                                             const float* __restrict__ bhh) {
  __shared__ float At[64 * 34];
  __shared__ float Bt[64 * 200];
  const int t = threadIdx.x;
  const int n0 = blockIdx.x * 32;
  const int tn = t >> 4, to = t & 15;

  for (int p = t; p < 32 * 64; p += 256) {
    int n = p >> 6, k = p & 63;
    At[k * 34 + n] = (n0 + n < NN) ? xc[(n0 + n) * 64 + k] : 0.0f;
  }
  for (int p = t; p < 192 * 64; p += 256) {
    int o = p >> 6, k = p & 63;
    Bt[k * 200 + o] = Wih[p];
  }
  __syncthreads();
  float ai[2][3][4], ah[2][3][4];
#pragma unroll
  for (int j = 0; j < 3; j++)
#pragma unroll
    for (int hh = 0; hh < 4; hh++) {
      float bv = bih[j * 64 + to * 4 + hh];
      ai[0][j][hh] = bv; ai[1][j][hh] = bv;
      float bv2 = bhh[j * 64 + to * 4 + hh];
      ah[0][j][hh] = bv2; ah[1][j][hh] = bv2;
    }
  for (int k = 0; k < 64; k++) {
    f32x2 a = *reinterpret_cast<const f32x2*>(&At[k * 34 + tn * 2]);
#pragma unroll
    for (int j = 0; j < 3; j++) {
      f32x4 b = *reinterpret_cast<const f32x4*>(&Bt[k * 200 + j * 64 + to * 4]);
#pragma unroll
      for (int hh = 0; hh < 4; hh++) {
        ai[0][j][hh] += a[0] * b[hh];
        ai[1][j][hh] += a[1] * b[hh];
      }
    }
  }
  __syncthreads();
  for (int p = t; p < 32 * 64; p += 256) {
    int n = p >> 6, k = p & 63;
    At[k * 34 + n] = (n0 + n < NN) ? x[(n0 + n) * 64 + k] : 0.0f;
  }
  for (int p = t; p < 192 * 64; p += 256) {
    int o = p >> 6, k = p & 63;
    Bt[k * 200 + o] = Whh[p];
  }
  __syncthreads();
  for (int k = 0; k < 64; k++) {
    f32x2 a = *reinterpret_cast<const f32x2*>(&At[k * 34 + tn * 2]);
#pragma unroll
    for (int j = 0; j < 3; j++) {
      f32x4 b = *reinterpret_cast<const f32x4*>(&Bt[k * 200 + j * 64 + to * 4]);
#pragma unroll
      for (int hh = 0; hh < 4; hh++) {
        ah[0][j][hh] += a[0] * b[hh];
        ah[1][j][hh] += a[1] * b[hh];
      }
    }
  }
#pragma unroll
  for (int nn = 0; nn < 2; nn++) {
    int n = n0 + tn * 2 + nn;
    if (n < NN) {
      f32x4 xn;
#pragma unroll
      for (int hh = 0; hh < 4; hh++) {
        float r = sigm(ai[nn][0][hh] + ah[nn][0][hh]);
        float z = sigm(ai[nn][1][hh] + ah[nn][1][hh]);
        float ng = tanhf(ai[nn][2][hh] + r * ah[nn][2][hh]);
        float hold = At[(to * 4 + hh) * 34 + tn * 2 + nn];
        xn[hh] = (1.0f - z) * ng + z * hold;
      }
      *reinterpret_cast<f32x4*>(x + n * 64 + to * 4) = xn;
      unsigned p0 = (unsigned)f2b(xn[0]) | ((unsigned)f2b(xn[1]) << 16);
      unsigned p1 = (unsigned)f2b(xn[2]) | ((unsigned)f2b(xn[3]) << 16);
      *reinterpret_cast<uint2*>(xb + (size_t)n * 64 + to * 4) = make_uint2(p0, p1);
    }
  }
}

// ------------------------------- Set2Set -----------------------------------
// Fused LSTM step: consumes q_star = [hl | rr] implicitly, first-step init,
// zeroes rr/mmax/asum for the following accumulation kernels.
__global__ __launch_bounds__(64) void k_lstm(const float* __restrict__ Wih,
                                             const float* __restrict__ Whh,
                                             const float* __restrict__ bih,
                                             const float* __restrict__ bhh,
                                             float* hl, float* cl, float* rr,
                                             unsigned* mmax, float* asum, int first) {
  int b = blockIdx.x, lane = threadIdx.x;
  float g[4];
#pragma unroll
  for (int j = 0; j < 4; j++) {
    int row = j * 64 + lane;
    float acc = bih[row] + bhh[row];
    if (!first) {
      for (int k = 0; k < 64; k++)
        acc += hl[b * 64 + k] * (Wih[row * 128 + k] + Whh[row * 64 + k]);
      for (int k = 0; k < 64; k++)
        acc += rr[b * 64 + k] * Wih[row * 128 + 64 + k];
    }
    g[j] = acc;
  }
  float cprev = first ? 0.0f : cl[b * 64 + lane];
  float ig = sigm(g[0]), fg = sigm(g[1]), gg = tanhf(g[2]), og = sigm(g[3]);
  float c = fg * cprev + ig * gg;
  cl[b * 64 + lane] = c;
  hl[b * 64 + lane] = og * tanhf(c);
  rr[b * 64 + lane] = 0.0f;
  if (lane == 0) { mmax[b] = 0u; asum[b] = 0.0f; }
}

__global__ __launch_bounds__(256) void k_edot(const float* __restrict__ x,
                                              const float* __restrict__ hl,
                                              const int* __restrict__ batch,
                                              float* __restrict__ e_buf,
                                              unsigned* __restrict__ mmax) {
  int node = blockIdx.x * 4 + (threadIdx.x >> 6);
  int lane = threadIdx.x & 63;
  int b = batch[node];
  float v = x[node * 64 + lane] * hl[b * 64 + lane];
#pragma unroll
  for (int mm = 32; mm; mm >>= 1) v += __shfl_xor(v, mm, 64);
  if (lane == 0) {
    e_buf[node] = v;
    atomicMax(mmax + b, encf(v));
  }
}

__global__ __launch_bounds__(256) void k_asum(const float* __restrict__ e_buf,
                                              const int* __restrict__ batch,
                                              const unsigned* __restrict__ mmax,
                                              float* __restrict__ a_buf,
                                              float* __restrict__ asum) {
  int n = blockIdx.x * 256 + threadIdx.x;
  if (n < NN) {
    int b = batch[n];
    unsigned u = mmax[b];
    float ev = e_buf[n];
    float mx = (u == 0u) ? ev : decf(u);
    float a = __expf(ev - mx);
    a_buf[n] = a;
    atomicAdd(asum + b, a);
  }
}

__global__ __launch_bounds__(256) void k_rread(const float* __restrict__ x,
                                               const int* __restrict__ batch,
                                               const float* __restrict__ a_buf,
                                               const float* __restrict__ asum,
                                               float* __restrict__ rr) {
  int node = blockIdx.x * 4 + (threadIdx.x >> 6);
  int lane = threadIdx.x & 63;
  int b = batch[node];
  float wgt = a_buf[node] / asum[b];
  atomicAdd(rr + (size_t)b * 64 + lane, wgt * x[node * 64 + lane]);
}

__global__ __launch_bounds__(64) void k_out(const float* __restrict__ hl,
                                            const float* __restrict__ rr,
                                            const float* __restrict__ W1,
                                            const float* __restrict__ b1,
                                            const float* __restrict__ W2,
                                            const float* __restrict__ b2o,
                                            void* __restrict__ out,
                                            const int* __restrict__ flag) {
  int b = blockIdx.x, lane = threadIdx.x;
  float acc = b1[lane];
  for (int k = 0; k < 64; k++) acc += hl[b * 64 + k] * W1[lane * 128 + k];
  for (int k = 0; k < 64; k++) acc += rr[b * 64 + k] * W1[lane * 128 + 64 + k];
  float u = siluf(acc) * W2[lane];
#pragma unroll
  for (int mm = 32; mm; mm >>= 1) u += __shfl_xor(u, mm, 64);
  if (lane == 0) {
    float v = u + b2o[0];
    if (*flag) ((unsigned short*)out)[b] = f2b(v);
    else ((float*)out)[b] = v;
  }
}

// ---------------------------------------------------------------------------
template <int KC>
static void run_chunks(const unsigned short* xb, const unsigned short* W2t,
                       unsigned short* Tc, const unsigned short* s_bf,
                       const int* ei, float* m, hipStream_t stream) {
  const int nch = 128 / KC;
  for (int c = 0; c < nch; c++) {
    k_T<KC><<<dim3((NN + 127) / 128, (64 * KC) / 128), 256, 0, stream>>>(xb, W2t, Tc, c * KC);
    k_emsg<KC><<<EE / 4, 256, 0, stream>>>(Tc, s_bf, ei, m, c * KC, c == 0 ? 1 : 0);
  }
}

extern "C" void kernel_launch(void* const* d_in, const int* in_sizes, int n_in,
                              void* d_out, int out_size, void* d_ws, size_t ws_size,
                              hipStream_t stream) {
  (void)n_in; (void)out_size;
  const bool sig_order = (in_sizes[1] == 2 * EE);
  const void* p_x   = d_in[0];
  const void* p_ea  = sig_order ? d_in[2] : d_in[1];
  const void* p_pos = sig_order ? d_in[3] : d_in[2];
  const int* edge_index = (const int*)(sig_order ? d_in[1] : d_in[3]);
  const int* batch      = (const int*)d_in[4];
  const void* p_w[20];
  for (int i = 0; i < 20; i++) p_w[i] = d_in[5 + i];

  char* base = (char*)d_ws;
  size_t off = 0;
  auto alloc = [&](size_t bytes) -> char* {
    char* p = base + off;
    off = (off + bytes + 255) & ~(size_t)255;
    return p;
  };
  int* flag = (int*)alloc(4);
  static const int cvt_n[NCVT] = {
      NN * 11, EE * 4, NN * 3,
      64 * 11, 64, 128 * 5, 128, 4096 * 128, 4096,
      64 * 64, 64,
      192 * 64, 192 * 64, 192, 192,
      256 * 128, 256 * 64, 256, 256,
      64 * 128, 64, 64, 1};
  float* canon[NCVT];
  for (int i = 0; i < NCVT; i++) canon[i] = (float*)alloc((size_t)cvt_n[i] * 4);
  const float* c_x    = canon[0];
  const float* c_ea   = canon[1];
  const float* c_pos  = canon[2];
  const float* c_flW  = canon[3];
  const float* c_flb  = canon[4];
  const float* c_W1   = canon[5];
  const float* c_b1   = canon[6];
  const float* c_W2   = canon[7];
  const float* c_b2   = canon[8];
  const float* c_rW   = canon[9];
  const float* c_rb   = canon[10];
  const float* c_gWih = canon[11];
  const float* c_gWhh = canon[12];
  const float* c_gbih = canon[13];
  const float* c_gbhh = canon[14];
  const float* c_lWih = canon[15];
  const float* c_lWhh = canon[16];
  const float* c_lbih = canon[17];
  const float* c_lbhh = canon[18];
  const float* c_oW1  = canon[19];
  const float* c_ob1  = canon[20];
  const float* c_oW2  = canon[21];
  const float* c_ob2  = canon[22];

  unsigned short* s_bf = (unsigned short*)alloc((size_t)EE * 128 * 2);  // 12.8MB
  float* m    = (float*)alloc((size_t)EE * 64 * 4);                     // fallback only
  float* x    = (float*)alloc((size_t)NN * 64 * 4);
  unsigned short* xb = (unsigned short*)alloc((size_t)NN * 64 * 2);
  float* xc   = (float*)alloc((size_t)NN * 64 * 4);
  float* agg  = (float*)alloc((size_t)NN * 64 * 4);
  float* xb2  = (float*)alloc((size_t)NN * 64 * 4);
  unsigned short* W2t = (unsigned short*)alloc((size_t)4096 * 128 * 2); // 1MB
  float* invd = (float*)alloc((size_t)NN * 4);
  int* cnt    = (int*)alloc((size_t)2 * NN * 4);  // cnt | cntd (one memset)
  int* cntd   = cnt + NN;
  int* eptr   = (int*)alloc((size_t)(NN + 1) * 4);
  int* cursor = (int*)alloc((size_t)NN * 4);
  int* eord   = (int*)alloc((size_t)EE * 4);
  float* hl   = (float*)alloc((size_t)BBG * 64 * 4);
  float* cl   = (float*)alloc((size_t)BBG * 64 * 4);
  unsigned* mmax = (unsigned*)alloc((size_t)BBG * 4);
  float* asum = (float*)alloc((size_t)BBG * 4);
  float* rr   = (float*)alloc((size_t)BBG * 64 * 4);
  float* e_buf = (float*)alloc((size_t)NN * 4);
  float* a_buf = (float*)alloc((size_t)NN * 4);
  size_t base_need = off;

  int KC = 0;
  const int kcs[5] = {128, 64, 32, 16, 8};
  for (int i = 0; i < 5; i++) {
    size_t need = base_need + (size_t)NN * 64 * kcs[i] * 2 + 256;
    if (need <= ws_size) { KC = kcs[i]; break; }
  }
  if (KC == 0) return;
  unsigned short* Tc = (unsigned short*)alloc((size_t)NN * 64 * KC * 2);

  // ---- dtype detect + convert ----
  k_detect<<<1, 256, 0, stream>>>((const unsigned*)p_ea, flag);
  Cvt cvt;
  cvt.src[0] = p_x; cvt.src[1] = p_ea; cvt.src[2] = p_pos;
  for (int i = 0; i < 20; i++) cvt.src[3 + i] = p_w[i];
  for (int i = 0; i < NCVT; i++) { cvt.dst[i] = canon[i]; cvt.n[i] = cvt_n[i]; }
  k_convert<<<512, 256, 0, stream>>>(cvt, flag);

  // ---- prologue ----
  hipMemsetAsync(cnt, 0, (size_t)2 * NN * 4, stream);
  k_lift<<<NN / 4, 256, 0, stream>>>(c_x, c_flW, c_flb, x, xb);
  k_sdeg<<<EE / 2, 256, 0, stream>>>(c_ea, c_pos, edge_index, c_W1, c_b1, s_bf);
  k_w2t<<<(4096 * 128) / 256, 256, 0, stream>>>(c_W2, W2t);
  k_hist<<<(EE + 255) / 256, 256, 0, stream>>>(edge_index, cnt, cntd);
  k_scan<<<1, 256, 0, stream>>>(cnt, cntd, eptr, cursor, invd);
  k_scatter<<<(EE + 255) / 256, 256, 0, stream>>>(edge_index, cursor, eord);

  // ---- 4 message-passing layers ----
  for (int layer = 0; layer < 4; layer++) {
    k_xb2<<<NN / 4, 256, 0, stream>>>(x, c_b2, xb2, agg);  // also zeroes agg
    if (KC == 128) {
      k_T<128><<<dim3((NN + 127) / 128, 64), 256, 0, stream>>>(xb, W2t, Tc, 0);
      k_group<<<NN, 64, 0, stream>>>(Tc, s_bf, xb2, edge_index, eptr, eord, agg);
    } else {
      switch (KC) {
        case 64: run_chunks<64>(xb, W2t, Tc, s_bf, edge_index, m, stream); break;
        case 32: run_chunks<32>(xb, W2t, Tc, s_bf, edge_index, m, stream); break;
        case 16: run_chunks<16>(xb, W2t, Tc, s_bf, edge_index, m, stream); break;
        default: run_chunks<8>(xb, W2t, Tc, s_bf, edge_index, m, stream); break;
      }
      k_aggm<<<EE / 4, 256, 0, stream>>>(m, xb2, edge_index, agg);
    }
    k_xc<<<(NN + 31) / 32, 256, 0, stream>>>(x, agg, invd, c_rW, c_rb, xc);
    k_gru<<<(NN + 31) / 32, 256, 0, stream>>>(xc, x, xb, c_gWih, c_gWhh, c_gbih, c_gbhh);
  }

  // ---- Set2Set (no memsets: k_lstm handles init/zeroing) ----
  for (int step = 0; step < 3; step++) {
    k_lstm<<<BBG, 64, 0, stream>>>(c_lWih, c_lWhh, c_lbih, c_lbhh, hl, cl, rr,
                                   mmax, asum, step == 0 ? 1 : 0);
    k_edot<<<NN / 4, 256, 0, stream>>>(x, hl, batch, e_buf, mmax);
    k_asum<<<(NN + 255) / 256, 256, 0, stream>>>(e_buf, batch, mmax, a_buf, asum);
    k_rread<<<NN / 4, 256, 0, stream>>>(x, batch, a_buf, asum, rr);
  }

  // ---- output head ----
  k_out<<<BBG, 64, 0, stream>>>(hl, rr, c_oW1, c_ob1, c_oW2, c_ob2, d_out, flag);
}